// Round 8
// baseline (304.187 us; speedup 1.0000x reference)
//
#include <hip/hip_runtime.h>
#include <math.h>

#define SEQ 2516
#define SEQP 2520
#define SEQP2 2560
#define CDIM 128

typedef __attribute__((ext_vector_type(8))) short short8;
typedef __attribute__((ext_vector_type(4))) float f32x4;

__device__ __forceinline__ float gelu_exact(float x) {
    return x * 0.5f * (1.0f + erff(x * 0.7071067811865475f));
}
__device__ __forceinline__ float fexp2(float x) { return __builtin_amdgcn_exp2f(x); }
__device__ __forceinline__ short f2bf(float f) {     // fp32 -> bf16 RNE
    unsigned u = __float_as_uint(f);
    unsigned r = 0x7fffu + ((u >> 16) & 1u);
    return (short)((u + r) >> 16);
}
__device__ __forceinline__ short f2bf_trunc(float f) {   // for P (e>=0): 1 op
    return (short)(__float_as_uint(f) >> 16);
}

// ------------- concat + LN1(layer0): one wave per row; H stored bf16 ------------
__global__ __launch_bounds__(64) void concat_ln_kernel(
    const float* __restrict__ td, const float* __restrict__ sup,
    const float* __restrict__ g, const float* __restrict__ b,
    float* __restrict__ X, short* __restrict__ Hbf) {
    const int row = blockIdx.x;
    const int t = threadIdx.x;
    float x0, x1;
    if (row < 16) {
        x0 = td[row * 128 + t];
        x1 = td[row * 128 + 64 + t];
    } else {
        int r = row - 16;
        int n = r / 100, p = r - n * 100;
        x0 = sup[n * 12800 + t * 100 + p];
        x1 = sup[n * 12800 + (t + 64) * 100 + p];
    }
    X[row * 128 + t] = x0;
    X[row * 128 + 64 + t] = x1;
    float s = x0 + x1;
    for (int off = 32; off > 0; off >>= 1) s += __shfl_down(s, off);
    float mean = __shfl(s, 0) * (1.f / 128.f);
    float d0 = x0 - mean, d1 = x1 - mean;
    float v = d0 * d0 + d1 * d1;
    for (int off = 32; off > 0; off >>= 1) v += __shfl_down(v, off);
    float var = __shfl(v, 0) * (1.f / 128.f);
    float rstd = rsqrtf(var + 1e-5f);
    Hbf[row * 128 + t]      = f2bf(d0 * rstd * g[t] + b[t]);
    Hbf[row * 128 + 64 + t] = f2bf(d1 * rstd * g[t + 64] + b[t + 64]);
}

// ---- qkv MFMA GEMM: A is pre-converted bf16 (Hbf). Writes Q/K bf16, V^T bf16 ---
__global__ __launch_bounds__(256) void qkv_mfma_kernel(
    const short* __restrict__ A, const float* __restrict__ W,
    const float* __restrict__ bias,
    short* __restrict__ Qbf, short* __restrict__ Kbf, short* __restrict__ VTb,
    int q_mt) {
    if (blockIdx.y < 2 && (int)blockIdx.x >= q_mt) return;   // uniform: whole block
    __shared__ __align__(16) short Wt[64 * 136];   // 17.4 KB
    const int t = threadIdx.x;
    const int wave = t >> 6, lane = t & 63;
    const int quad = lane >> 4, c16 = lane & 15;
    const int m0 = blockIdx.x * 64;
    const int n0 = blockIdx.y * 64;
    const float SC = 0.25f * 1.4426950408889634f;   // folded into Q
    #pragma unroll
    for (int pass = 0; pass < 4; ++pass) {
        int idx = t + pass * 256;
        int n = idx & 63, kc = idx >> 6;
        short8 wv;
        #pragma unroll
        for (int j = 0; j < 8; ++j)
            wv[j] = f2bf(W[(size_t)(kc * 8 + j) * 384 + n0 + n]);
        *(short8*)&Wt[n * 136 + kc * 8] = wv;
    }
    __syncthreads();
    const int am = m0 + wave * 16 + c16;
    f32x4 acc[4];
    #pragma unroll
    for (int i = 0; i < 4; ++i) acc[i] = (f32x4){0.f, 0.f, 0.f, 0.f};
    #pragma unroll
    for (int kk = 0; kk < 4; ++kk) {
        short8 af = *(const short8*)(A + (size_t)am * 128 + kk * 32 + quad * 8);
        #pragma unroll
        for (int ns = 0; ns < 4; ++ns) {
            short8 wf = *(const short8*)&Wt[(ns * 16 + c16) * 136 + kk * 32 + quad * 8];
            acc[ns] = __builtin_amdgcn_mfma_f32_16x16x32_bf16(af, wf, acc[ns], 0, 0, 0);
        }
    }
    const int region = __builtin_amdgcn_readfirstlane(n0 >> 7);  // 0 Q, 1 K, 2 V
    #pragma unroll
    for (int ns = 0; ns < 4; ++ns) {
        const int n = n0 + ns * 16 + c16;
        float bv = bias[n];
        #pragma unroll
        for (int r = 0; r < 4; ++r) {
            const int row = m0 + wave * 16 + quad * 4 + r;
            float v = acc[ns][r] + bv;
            if (region == 0)      Qbf[(size_t)row * 128 + n] = f2bf(v * SC);
            else if (region == 1) Kbf[(size_t)row * 128 + (n - 128)] = f2bf(v);
            else                  VTb[(size_t)(n - 256) * SEQP2 + row] = f2bf(v);
        }
    }
}

// ---- attention: bf16 MFMA flash, 4 waves / 64 q-rows per block, split-K=2 ------
// K/V staged once per block per tile (shared by 4 waves) -> half the staging
// traffic and half the barrier instances of the old 2-wave version.
__global__ __launch_bounds__(256) void attn_kernel(
    const short* __restrict__ Qbf, const short* __restrict__ Kbf,
    const short* __restrict__ VTb, float* __restrict__ PART) {
    __shared__ __align__(16) short sKs[13952];  // Ks 128*24 | Vt 16*136 | P 4*16*136
    short* Ks = sKs;
    short* Vt = sKs + 3072;
    const int t = threadIdx.x;
    const int wave = t >> 6, lane = t & 63;
    const int quad = lane >> 4, c16 = lane & 15;
    short* Pw = sKs + 3072 + 2176 + wave * 2176;
    const int head = blockIdx.y, z = blockIdx.z;
    const int qb = blockIdx.x * 64 + wave * 16;

    short8 qf;
    #pragma unroll
    for (int i = 0; i < 8; ++i) qf[i] = 0;
    if (quad < 2)
        qf = *(const short8*)(Qbf + (size_t)(qb + c16) * 128 + head * 16 + quad * 8);
    f32x4 oacc = {0.f, 0.f, 0.f, 0.f};
    float m_[4] = {-INFINITY, -INFINITY, -INFINITY, -INFINITY};
    float l_[4] = {0.f, 0.f, 0.f, 0.f};

    const int krow = t >> 1, khalf = t & 1;       // K staging: 2 threads/row
    const int vdim = t >> 4, vseg = t & 15;       // V staging: 16 threads/dim
    const int tA = z * 10, tB = z ? 20 : 10;
    for (int ti = tA; ti < tB; ++ti) {
        const int tile0 = ti * 128;
        if (ti != tA) __syncthreads();
        {
            const short8* kp = (const short8*)(Kbf + (size_t)(tile0 + krow) * 128 + head * 16) + khalf;
            *(short8*)&Ks[krow * 24 + khalf * 8] = kp[0];
            const short8* vp = (const short8*)(VTb + (size_t)(head * 16 + vdim) * SEQP2 + tile0 + vseg * 8);
            *(short8*)&Vt[vdim * 136 + vseg * 8] = vp[0];
        }
        __syncthreads();

        f32x4 sA[4], sB[4];
        #pragma unroll
        for (int st = 0; st < 4; ++st) {
            const int k0 = st * 32;
            short8 kfA, kfB;
            #pragma unroll
            for (int i = 0; i < 8; ++i) { kfA[i] = 0; kfB[i] = 0; }
            if (quad < 2) {
                kfA = *(const short8*)&Ks[(k0 + c16) * 24 + quad * 8];
                kfB = *(const short8*)&Ks[(k0 + 16 + c16) * 24 + quad * 8];
            }
            f32x4 zz = {0.f, 0.f, 0.f, 0.f};
            sA[st] = __builtin_amdgcn_mfma_f32_16x16x32_bf16(qf, kfA, zz, 0, 0, 0);
            sB[st] = __builtin_amdgcn_mfma_f32_16x16x32_bf16(qf, kfB, zz, 0, 0, 0);
            const bool badA = (tile0 + k0 + c16) >= SEQ;
            const bool badB = (tile0 + k0 + 16 + c16) >= SEQ;
            if (badA) { sA[st][0] = -1e30f; sA[st][1] = -1e30f; sA[st][2] = -1e30f; sA[st][3] = -1e30f; }
            if (badB) { sB[st][0] = -1e30f; sB[st][1] = -1e30f; sB[st][2] = -1e30f; sB[st][3] = -1e30f; }
        }
        #pragma unroll
        for (int r = 0; r < 4; ++r) {
            float v = fmaxf(sA[0][r], sB[0][r]);
            #pragma unroll
            for (int st = 1; st < 4; ++st) v = fmaxf(v, fmaxf(sA[st][r], sB[st][r]));
            v = fmaxf(v, __shfl_xor(v, 1));
            v = fmaxf(v, __shfl_xor(v, 2));
            v = fmaxf(v, __shfl_xor(v, 4));
            v = fmaxf(v, __shfl_xor(v, 8));
            float nm = fmaxf(m_[r], v);
            float corr = fexp2(m_[r] - nm);
            m_[r] = nm;
            oacc[r] *= corr;
            l_[r] *= corr;
        }
        #pragma unroll
        for (int st = 0; st < 4; ++st) {
            #pragma unroll
            for (int r = 0; r < 4; ++r) {
                float eA = fexp2(sA[st][r] - m_[r]);
                float eB = fexp2(sB[st][r] - m_[r]);
                l_[r] += eA + eB;
                Pw[(quad * 4 + r) * 136 + st * 32 + c16]      = f2bf_trunc(eA);
                Pw[(quad * 4 + r) * 136 + st * 32 + 16 + c16] = f2bf_trunc(eB);
            }
        }
        #pragma unroll
        for (int st = 0; st < 4; ++st) {
            short8 pf = *(const short8*)&Pw[c16 * 136 + st * 32 + quad * 8];
            short8 vf = *(const short8*)&Vt[c16 * 136 + st * 32 + quad * 8];
            oacc = __builtin_amdgcn_mfma_f32_16x16x32_bf16(pf, vf, oacc, 0, 0, 0);
        }
    }
    #pragma unroll
    for (int r = 0; r < 4; ++r) {
        float lr = l_[r];
        lr += __shfl_xor(lr, 1);
        lr += __shfl_xor(lr, 2);
        lr += __shfl_xor(lr, 4);
        lr += __shfl_xor(lr, 8);
        const int qrow = qb + quad * 4 + r;
        if (qrow < SEQ) {
            float* dst = PART + ((size_t)(z * 8 + head) * SEQP + qrow) * 20;
            dst[c16] = oacc[r];
            if (c16 == 0) { dst[16] = m_[r]; dst[17] = lr; }
        }
    }
}

// ---- proj GEMM fused with attn 2-way split merge + residual + row-LN -----------
__global__ __launch_bounds__(512) void proj_merge_ln_kernel(
    const float* __restrict__ PART, const float* __restrict__ W,
    const float* __restrict__ bias, const float* __restrict__ R,
    float* __restrict__ C, short* __restrict__ Hbf,
    const float* __restrict__ g, const float* __restrict__ bb, int M) {
    __shared__ float ln[8][130];
    const int t = threadIdx.x;
    const int c = t & 127;
    const int grp = __builtin_amdgcn_readfirstlane(t >> 7);
    const int r0 = blockIdx.x * 8 + grp * 2;
    float acc0 = 0.f, acc1 = 0.f;
    #pragma unroll
    for (int h = 0; h < 8; ++h) {
        const float* p0a = PART + ((size_t)h * SEQP + r0) * 20;
        const float* p1a = PART + ((size_t)(8 + h) * SEQP + r0) * 20;
        const float* p0b = p0a + 20;
        const float* p1b = p1a + 20;
        float m0 = p0a[16], l0 = p0a[17], m1 = p1a[16], l1 = p1a[17];
        float Ma = fmaxf(m0, m1);
        float w0 = fexp2(m0 - Ma), w1 = fexp2(m1 - Ma);
        float inva = 1.f / fmaf(l0, w0, l1 * w1);
        float c0a = w0 * inva, c1a = w1 * inva;
        m0 = p0b[16]; l0 = p0b[17]; m1 = p1b[16]; l1 = p1b[17];
        float Mb = fmaxf(m0, m1);
        w0 = fexp2(m0 - Mb); w1 = fexp2(m1 - Mb);
        float invb = 1.f / fmaf(l0, w0, l1 * w1);
        float c0b = w0 * invb, c1b = w1 * invb;
        #pragma unroll
        for (int kk = 0; kk < 4; ++kk) {
            const int k0 = h * 16 + kk * 4;
            float w_0 = W[(size_t)(k0 + 0) * 128 + c];
            float w_1 = W[(size_t)(k0 + 1) * 128 + c];
            float w_2 = W[(size_t)(k0 + 2) * 128 + c];
            float w_3 = W[(size_t)(k0 + 3) * 128 + c];
            float4 x0 = *(const float4*)&p0a[kk * 4];
            float4 y0 = *(const float4*)&p1a[kk * 4];
            float4 x1 = *(const float4*)&p0b[kk * 4];
            float4 y1 = *(const float4*)&p1b[kk * 4];
            float a00 = x0.x * c0a + y0.x * c1a;
            float a01 = x0.y * c0a + y0.y * c1a;
            float a02 = x0.z * c0a + y0.z * c1a;
            float a03 = x0.w * c0a + y0.w * c1a;
            float a10 = x1.x * c0b + y1.x * c1b;
            float a11 = x1.y * c0b + y1.y * c1b;
            float a12 = x1.z * c0b + y1.z * c1b;
            float a13 = x1.w * c0b + y1.w * c1b;
            acc0 = fmaf(a00, w_0, acc0); acc0 = fmaf(a01, w_1, acc0);
            acc0 = fmaf(a02, w_2, acc0); acc0 = fmaf(a03, w_3, acc0);
            acc1 = fmaf(a10, w_0, acc1); acc1 = fmaf(a11, w_1, acc1);
            acc1 = fmaf(a12, w_2, acc1); acc1 = fmaf(a13, w_3, acc1);
        }
    }
    float bv = bias[c];
    float v0 = acc0 + bv + R[(size_t)(r0 + 0) * 128 + c];
    float v1 = acc1 + bv + R[(size_t)(r0 + 1) * 128 + c];
    ln[grp * 2 + 0][c] = v0;
    ln[grp * 2 + 1][c] = v1;
    if (r0 + 0 < M) C[(size_t)(r0 + 0) * 128 + c] = v0;
    if (r0 + 1 < M) C[(size_t)(r0 + 1) * 128 + c] = v1;
    __syncthreads();
    const int wv = t >> 6, l = t & 63;
    float x0 = ln[wv][l], x1 = ln[wv][l + 64];
    float s = x0 + x1;
    for (int off = 32; off > 0; off >>= 1) s += __shfl_down(s, off);
    float mean = __shfl(s, 0) * (1.f / 128.f);
    float d0 = x0 - mean, d1 = x1 - mean;
    float vv = d0 * d0 + d1 * d1;
    for (int off = 32; off > 0; off >>= 1) vv += __shfl_down(vv, off);
    float var = __shfl(vv, 0) * (1.f / 128.f);
    float rstd = rsqrtf(var + 1e-5f);
    const int hrow = blockIdx.x * 8 + wv;
    Hbf[(size_t)hrow * 128 + l]      = f2bf(d0 * rstd * g[l] + bb[l]);
    Hbf[(size_t)hrow * 128 + 64 + l] = f2bf(d1 * rstd * g[l + 64] + bb[l + 64]);
}

// ---- FUSED mlp1+mlp2-kpart: grid (M-tiles, 8 kz); A is bf16 (Hbf) --------------
__global__ __launch_bounds__(256) void mlp_fused_kernel(
    const short* __restrict__ A, const float* __restrict__ W1,
    const float* __restrict__ b1, const float* __restrict__ W2,
    float* __restrict__ PARTG) {
    __shared__ __align__(16) short W1t[64 * 136];   // 17.4 KB
    __shared__ __align__(16) short W2t[128 * 72];   // 18.4 KB
    __shared__ __align__(16) short Ct[4 * 16 * 72]; //  9.2 KB (per-wave 16x72)
    const int t = threadIdx.x;
    const int wave = t >> 6, lane = t & 63;
    const int quad = lane >> 4, c16 = lane & 15;
    const int m0 = blockIdx.x * 64;
    const int kz = blockIdx.y;
    const int n0 = kz * 64;
    #pragma unroll
    for (int pass = 0; pass < 4; ++pass) {
        int idx = t + pass * 256;
        int n = idx & 63, kc = idx >> 6;
        short8 wv;
        #pragma unroll
        for (int j = 0; j < 8; ++j)
            wv[j] = f2bf(W1[(size_t)(kc * 8 + j) * 512 + n0 + n]);
        *(short8*)&W1t[n * 136 + kc * 8] = wv;
    }
    {
        const int n = t & 127, half = t >> 7;
        #pragma unroll
        for (int c = 0; c < 4; ++c) {
            short8 wv;
            #pragma unroll
            for (int j = 0; j < 8; ++j)
                wv[j] = f2bf(W2[(size_t)(n0 + half * 32 + c * 8 + j) * 128 + n]);
            *(short8*)&W2t[n * 72 + half * 32 + c * 8] = wv;
        }
    }
    __syncthreads();
    const int am = m0 + wave * 16 + c16;
    f32x4 acc1[4];
    #pragma unroll
    for (int i = 0; i < 4; ++i) acc1[i] = (f32x4){0.f, 0.f, 0.f, 0.f};
    #pragma unroll
    for (int kk = 0; kk < 4; ++kk) {
        short8 af = *(const short8*)(A + (size_t)am * 128 + kk * 32 + quad * 8);
        #pragma unroll
        for (int ns = 0; ns < 4; ++ns) {
            short8 wf = *(const short8*)&W1t[(ns * 16 + c16) * 136 + kk * 32 + quad * 8];
            acc1[ns] = __builtin_amdgcn_mfma_f32_16x16x32_bf16(af, wf, acc1[ns], 0, 0, 0);
        }
    }
    short* Cw = Ct + wave * 16 * 72;
    #pragma unroll
    for (int ns = 0; ns < 4; ++ns) {
        float bv = b1[n0 + ns * 16 + c16];
        #pragma unroll
        for (int r = 0; r < 4; ++r)
            Cw[(quad * 4 + r) * 72 + ns * 16 + c16] = f2bf(gelu_exact(acc1[ns][r] + bv));
    }
    f32x4 acc2[8];
    #pragma unroll
    for (int i = 0; i < 8; ++i) acc2[i] = (f32x4){0.f, 0.f, 0.f, 0.f};
    #pragma unroll
    for (int kk = 0; kk < 2; ++kk) {
        short8 af2 = *(const short8*)&Cw[c16 * 72 + kk * 32 + quad * 8];
        #pragma unroll
        for (int ns = 0; ns < 8; ++ns) {
            short8 wf = *(const short8*)&W2t[(ns * 16 + c16) * 72 + kk * 32 + quad * 8];
            acc2[ns] = __builtin_amdgcn_mfma_f32_16x16x32_bf16(af2, wf, acc2[ns], 0, 0, 0);
        }
    }
    float* dst = PARTG + (size_t)kz * SEQP2 * 128;
    #pragma unroll
    for (int ns = 0; ns < 8; ++ns) {
        #pragma unroll
        for (int r = 0; r < 4; ++r) {
            const int row = m0 + wave * 16 + quad * 4 + r;
            dst[(size_t)row * 128 + ns * 16 + c16] = acc2[ns][r];
        }
    }
}

// ---- combine 8 K-split partials + bias + residual + row-LN (+optional zero) ----
__global__ __launch_bounds__(512) void combine_ln_kernel(
    const float* __restrict__ PARTG, const float* __restrict__ bias,
    const float* __restrict__ R, float* __restrict__ C, short* __restrict__ Hbf,
    const float* __restrict__ g, const float* __restrict__ bb, int M,
    float* __restrict__ zk) {
    __shared__ float ln[8][130];
    const int t = threadIdx.x;
    if (zk != nullptr && blockIdx.x == 0) {
        #pragma unroll
        for (int i = 0; i < 4; ++i) zk[t + i * 512] = 0.f;
    }
    const int c = t & 127;
    const int grp = __builtin_amdgcn_readfirstlane(t >> 7);
    const int r0 = blockIdx.x * 8 + grp * 2;
    #pragma unroll
    for (int i = 0; i < 2; ++i) {
        const int row = r0 + i;
        float v = bias[c] + R[(size_t)row * 128 + c];
        #pragma unroll
        for (int kz = 0; kz < 8; ++kz)
            v += PARTG[(size_t)kz * SEQP2 * 128 + (size_t)row * 128 + c];
        ln[grp * 2 + i][c] = v;
        if (row < M) C[(size_t)row * 128 + c] = v;
    }
    __syncthreads();
    const int wv = t >> 6, l = t & 63;
    float x0 = ln[wv][l], x1 = ln[wv][l + 64];
    float s = x0 + x1;
    for (int off = 32; off > 0; off >>= 1) s += __shfl_down(s, off);
    float mean = __shfl(s, 0) * (1.f / 128.f);
    float d0 = x0 - mean, d1 = x1 - mean;
    float vv = d0 * d0 + d1 * d1;
    for (int off = 32; off > 0; off >>= 1) vv += __shfl_down(vv, off);
    float var = __shfl(vv, 0) * (1.f / 128.f);
    float rstd = rsqrtf(var + 1e-5f);
    const int hrow = blockIdx.x * 8 + wv;
    Hbf[(size_t)hrow * 128 + l]      = f2bf(d0 * rstd * g[l] + bb[l]);
    Hbf[(size_t)hrow * 128 + 64 + l] = f2bf(d1 * rstd * g[l + 64] + bb[l + 64]);
}

// ---- LAYER-1 TAIL: proj+merge+LN for 16 rows (redundant per block) + MLP kz-slice
__global__ __launch_bounds__(512) void pml16_kernel(
    const float* __restrict__ PART, const float* __restrict__ Wo,
    const float* __restrict__ ob, const float* __restrict__ g2,
    const float* __restrict__ bl2, const float* __restrict__ W1,
    const float* __restrict__ b1, const float* __restrict__ W2,
    const float* __restrict__ b2, const float* __restrict__ X,
    float* __restrict__ KEY0) {
    __shared__ __align__(16) char SMEM[4352 + 38912];
    short* hA   = (short*)SMEM;                  // 16 x 136 bf16 (persistent)
    char*  U    = SMEM + 4352;                   // union region
    float* PARTL = (float*)U;                    // 5120 f  [sh16][row16][20]
    float* coefL = PARTL + 5120;                 // 256 f   [row16][h8][2]
    float* xpL   = coefL + 256;                  // 16*130 f
    short* W1t  = (short*)U;                     // 64*136
    short* W2t  = W1t + 8704;                    // 128*72
    short* Ct   = W2t + 9216;                    // 16*72
    const int t = threadIdx.x;
    const int kz = blockIdx.x;

    for (int i = t; i < 5120; i += 512) {
        int sh = i / 320, rem = i - sh * 320;
        PARTL[i] = PART[((size_t)sh * SEQP) * 20 + rem];
    }
    __syncthreads();
    if (t < 128) {
        int row = t >> 3, h = t & 7;
        float ma = PARTL[h * 320 + row * 20 + 16];
        float la = PARTL[h * 320 + row * 20 + 17];
        float mb = PARTL[(8 + h) * 320 + row * 20 + 16];
        float lb = PARTL[(8 + h) * 320 + row * 20 + 17];
        float Mx = fmaxf(ma, mb);
        float w0 = fexp2(ma - Mx), w1 = fexp2(mb - Mx);
        float inv = 1.f / fmaf(la, w0, lb * w1);
        coefL[row * 16 + h * 2]     = w0 * inv;
        coefL[row * 16 + h * 2 + 1] = w1 * inv;
    }
    __syncthreads();
    const int c = t & 127;
    const int grp = t >> 7;
    float xv[4] = {0.f, 0.f, 0.f, 0.f};
    for (int h = 0; h < 8; ++h) {
        float c0v[4], c1v[4];
        #pragma unroll
        for (int i = 0; i < 4; ++i) {
            int row = grp * 4 + i;
            c0v[i] = coefL[row * 16 + h * 2];
            c1v[i] = coefL[row * 16 + h * 2 + 1];
        }
        #pragma unroll
        for (int d = 0; d < 16; ++d) {
            float w = Wo[(size_t)(h * 16 + d) * 128 + c];
            #pragma unroll
            for (int i = 0; i < 4; ++i) {
                int row = grp * 4 + i;
                float a = PARTL[h * 320 + row * 20 + d] * c0v[i]
                        + PARTL[(8 + h) * 320 + row * 20 + d] * c1v[i];
                xv[i] = fmaf(a, w, xv[i]);
            }
        }
    }
    #pragma unroll
    for (int i = 0; i < 4; ++i) {
        int row = grp * 4 + i;
        float v = xv[i] + ob[c] + X[(size_t)row * 128 + c];
        xpL[row * 130 + c] = v;
        if (kz == 0) atomicAdd(&KEY0[row * 128 + c], v + b2[c]);
    }
    __syncthreads();
    {
        const int wv6 = t >> 6, l = t & 63;
        #pragma unroll
        for (int rr = 0; rr < 2; ++rr) {
            int row = wv6 * 2 + rr;
            float x0 = xpL[row * 130 + l], x1 = xpL[row * 130 + 64 + l];
            float s = x0 + x1;
            s += __shfl_xor(s, 1); s += __shfl_xor(s, 2); s += __shfl_xor(s, 4);
            s += __shfl_xor(s, 8); s += __shfl_xor(s, 16); s += __shfl_xor(s, 32);
            float mean = s * (1.f / 128.f);
            float d0 = x0 - mean, d1 = x1 - mean;
            float vv = d0 * d0 + d1 * d1;
            vv += __shfl_xor(vv, 1); vv += __shfl_xor(vv, 2); vv += __shfl_xor(vv, 4);
            vv += __shfl_xor(vv, 8); vv += __shfl_xor(vv, 16); vv += __shfl_xor(vv, 32);
            float rstd = rsqrtf(vv * (1.f / 128.f) + 1e-5f);
            hA[row * 136 + l]      = f2bf(d0 * rstd * g2[l] + bl2[l]);
            hA[row * 136 + 64 + l] = f2bf(d1 * rstd * g2[64 + l] + bl2[64 + l]);
        }
    }
    __syncthreads();   // xpL/PARTL dead; reuse U for weights
    for (int idx = t; idx < 1024; idx += 512) {
        int n = idx & 63, kc = idx >> 6;
        short8 wv;
        #pragma unroll
        for (int j = 0; j < 8; ++j)
            wv[j] = f2bf(W1[(size_t)(kc * 8 + j) * 512 + kz * 64 + n]);
        *(short8*)&W1t[n * 136 + kc * 8] = wv;
    }
    for (int idx = t; idx < 1024; idx += 512) {
        int n = idx & 127, kc = idx >> 7;
        short8 wv;
        #pragma unroll
        for (int j = 0; j < 8; ++j)
            wv[j] = f2bf(W2[(size_t)(kz * 64 + kc * 8 + j) * 128 + n]);
        *(short8*)&W2t[n * 72 + kc * 8] = wv;
    }
    __syncthreads();
    if (t < 64) {
        const int quad = t >> 4, c16 = t & 15;
        f32x4 acc1[4];
        #pragma unroll
        for (int i = 0; i < 4; ++i) acc1[i] = (f32x4){0.f, 0.f, 0.f, 0.f};
        #pragma unroll
        for (int kk = 0; kk < 4; ++kk) {
            short8 af = *(const short8*)&hA[c16 * 136 + kk * 32 + quad * 8];
            #pragma unroll
            for (int ns = 0; ns < 4; ++ns) {
                short8 wf = *(const short8*)&W1t[(ns * 16 + c16) * 136 + kk * 32 + quad * 8];
                acc1[ns] = __builtin_amdgcn_mfma_f32_16x16x32_bf16(af, wf, acc1[ns], 0, 0, 0);
            }
        }
        #pragma unroll
        for (int ns = 0; ns < 4; ++ns) {
            float bv = b1[kz * 64 + ns * 16 + c16];
            #pragma unroll
            for (int r = 0; r < 4; ++r)
                Ct[(quad * 4 + r) * 72 + ns * 16 + c16] = f2bf(gelu_exact(acc1[ns][r] + bv));
        }
        f32x4 acc2[8];
        #pragma unroll
        for (int i = 0; i < 8; ++i) acc2[i] = (f32x4){0.f, 0.f, 0.f, 0.f};
        #pragma unroll
        for (int kk = 0; kk < 2; ++kk) {
            short8 af2 = *(const short8*)&Ct[c16 * 72 + kk * 32 + quad * 8];
            #pragma unroll
            for (int ns = 0; ns < 8; ++ns) {
                short8 wf = *(const short8*)&W2t[(ns * 16 + c16) * 72 + kk * 32 + quad * 8];
                acc2[ns] = __builtin_amdgcn_mfma_f32_16x16x32_bf16(af2, wf, acc2[ns], 0, 0, 0);
            }
        }
        #pragma unroll
        for (int ns = 0; ns < 8; ++ns) {
            #pragma unroll
            for (int r = 0; r < 4; ++r)
                atomicAdd(&KEY0[(quad * 4 + r) * 128 + ns * 16 + c16], acc2[ns][r]);
        }
    }
}

// ---- region + stats + conv1-MFMA fused (grid 100); Wt DOUBLE-BUFFERED ----------
__global__ __launch_bounds__(256) void region_conv1_kernel(
    const float* __restrict__ sup, const float* __restrict__ qry,
    const float* __restrict__ KEY0, const float* __restrict__ rg,
    const float* __restrict__ rb, const float* __restrict__ w,
    short* __restrict__ C1, float* __restrict__ RFAC) {
    __shared__ __align__(16) short inT[144 * 136];     // 39.2 KB (key0L unioned)
    __shared__ __align__(16) short WtBuf[2][32 * 136]; // 17.4 KB
    __shared__ float rfacL[104], MEANL[104], RSTDL[104];
    const int b = blockIdx.x;
    const int t = threadIdx.x;
    const int wave = t >> 6, lane = t & 63;
    const int quad = lane >> 4, c16 = lane & 15;
    const float* feat = (b < 25) ? (sup + (size_t)b * 12800) : (qry + (size_t)(b - 25) * 12800);
    // P1: key0 into inT space (union), dots/stats
    float* key0L = (float*)inT;
    for (int i = t; i < 2048; i += 256) key0L[i] = KEY0[i];
    __syncthreads();
    if (t < 100) {
        float dots[16];
        #pragma unroll
        for (int mm = 0; mm < 16; ++mm) dots[mm] = 0.f;
        float s = 0.f, ss = 0.f;
        #pragma unroll 4
        for (int c = 0; c < 128; ++c) {
            float f = feat[c * 100 + t];
            s += f; ss = fmaf(f, f, ss);
            #pragma unroll
            for (int mm = 0; mm < 16; ++mm) dots[mm] = fmaf(f, key0L[mm * 128 + c], dots[mm]);
        }
        float m16 = 0.f;
        #pragma unroll
        for (int mm = 0; mm < 16; ++mm) m16 += 1.f / (1.f + expf(-dots[mm] * (1.f / 128.f)));
        float r = m16 * (1.f / 16.f) + 1.f;
        rfacL[t] = r;
        RFAC[b * 100 + t] = r;
        float mr = s * (1.f / 128.f);
        float vr = ss * (1.f / 128.f) - mr * mr;
        MEANL[t] = mr * r;
        RSTDL[t] = rsqrtf(vr * r * r + 1e-6f);
    }
    __syncthreads();       // key0L dead; inT reusable
    // P2: zero inT (halo must stay 0)
    for (int i = t; i < 2448; i += 256) {
        short8 z;
        #pragma unroll
        for (int j = 0; j < 8; ++j) z[j] = 0;
        *(short8*)&inT[i * 8] = z;
    }
    __syncthreads();
    // P3: fill interior + stage tap-0 weights (disjoint LDS regions)
    for (int i = t; i < 12800; i += 256) {
        int cc = i / 100, p = i - cc * 100;
        float v = feat[i] * rfacL[p];
        float lnv = (v - MEANL[p]) * RSTDL[p] * rg[cc] + rb[cc];
        int pos = (p / 10 + 1) * 12 + (p % 10) + 1;
        inT[pos * 136 + cc] = f2bf(lnv);
    }
    for (int i = t; i < 4096; i += 256) {
        int co = i >> 7, cin = i & 127;
        WtBuf[0][co * 136 + cin] = f2bf(w[(size_t)(co * 128 + cin) * 9]);
    }
    __syncthreads();
    const int m0 = wave * 32 + c16;
    const int m1 = m0 + 16;
    const int mc0 = (m0 < 100) ? m0 : 99, mc1 = (m1 < 100) ? m1 : 99;
    const int base0 = (mc0 / 10) * 12 + (mc0 % 10);
    const int base1 = (mc1 / 10) * 12 + (mc1 % 10);
    f32x4 a00 = {0.f,0.f,0.f,0.f}, a01 = {0.f,0.f,0.f,0.f};
    f32x4 a10 = {0.f,0.f,0.f,0.f}, a11 = {0.f,0.f,0.f,0.f};
    // P4: 9 taps, double-buffered weight staging overlaps MFMA
    for (int j = 0; j < 9; ++j) {
        short* Wcur = &WtBuf[j & 1][0];
        short* Wnxt = &WtBuf[(j & 1) ^ 1][0];
        if (j < 8) {
            for (int i = t; i < 4096; i += 256) {
                int co = i >> 7, cin = i & 127;
                Wnxt[co * 136 + cin] = f2bf(w[(size_t)(co * 128 + cin) * 9 + j + 1]);
            }
        }
        const int offj = (j / 3) * 12 + (j % 3);
        #pragma unroll
        for (int kk = 0; kk < 4; ++kk) {
            short8 af0 = *(const short8*)&inT[(base0 + offj) * 136 + kk * 32 + quad * 8];
            short8 af1 = *(const short8*)&inT[(base1 + offj) * 136 + kk * 32 + quad * 8];
            short8 bf0 = *(const short8*)&Wcur[c16 * 136 + kk * 32 + quad * 8];
            short8 bf1 = *(const short8*)&Wcur[(16 + c16) * 136 + kk * 32 + quad * 8];
            a00 = __builtin_amdgcn_mfma_f32_16x16x32_bf16(af0, bf0, a00, 0, 0, 0);
            a01 = __builtin_amdgcn_mfma_f32_16x16x32_bf16(af0, bf1, a01, 0, 0, 0);
            a10 = __builtin_amdgcn_mfma_f32_16x16x32_bf16(af1, bf0, a10, 0, 0, 0);
            a11 = __builtin_amdgcn_mfma_f32_16x16x32_bf16(af1, bf1, a11, 0, 0, 0);
        }
        __syncthreads();   // Wnxt complete + Wcur reads done before next iter
    }
    #pragma unroll
    for (int r = 0; r < 4; ++r) {
        const int p0 = wave * 32 + quad * 4 + r;
        const int p1 = p0 + 16;
        if (p0 < 100) {
            C1[((size_t)b * 100 + p0) * 32 + c16]      = f2bf(fmaxf(a00[r], 0.f));
            C1[((size_t)b * 100 + p0) * 32 + 16 + c16] = f2bf(fmaxf(a01[r], 0.f));
        }
        if (p1 < 100) {
            C1[((size_t)b * 100 + p1) * 32 + c16]      = f2bf(fmaxf(a10[r], 0.f));
            C1[((size_t)b * 100 + p1) * 32 + 16 + c16] = f2bf(fmaxf(a11[r], 0.f));
        }
    }
}

// ---- conv2+conv3+conv4+pool fused (grid 100, ping-pong LDS) --------------------
__global__ __launch_bounds__(256) void conv234_pool_kernel(
    const short* __restrict__ C1, const float* __restrict__ w2,
    const float* __restrict__ w3, const float* __restrict__ w4,
    const float* __restrict__ sup, const float* __restrict__ qry,
    const float* __restrict__ RFAC, float* __restrict__ out) {
    __shared__ __align__(16) short inTA[144 * 40];  // 11.5 KB
    __shared__ __align__(16) short inTB[144 * 40];  // 11.5 KB
    __shared__ __align__(16) short Wt[9 * 32 * 40]; // 23.0 KB (restaged per conv)
    __shared__ float sig[32 * 104];                 // 13.3 KB
    __shared__ float rfacL[104];
    const int b = blockIdx.x;
    const int t = threadIdx.x;
    const int wave = t >> 6, lane = t & 63;
    const int quad = lane >> 4, c16 = lane & 15;
    const float* feat = (b < 25) ? (sup + (size_t)b * 12800) : (qry + (size_t)(b - 25) * 12800);
    for (int i = t; i < 720; i += 256) {
        short8 z;
        #pragma unroll
        for (int j = 0; j < 8; ++j) z[j] = 0;
        *(short8*)&inTA[i * 8] = z;
        *(short8*)&inTB[i * 8] = z;
    }
    if (t < 100) rfacL[t] = RFAC[b * 100 + t];
    __syncthreads();
    for (int idx = t; idx < 200; idx += 256) {
        int pp = idx >> 1, half = idx & 1;
        int pos = (pp / 10 + 1) * 12 + (pp % 10) + 1;
        const short8* sp = (const short8*)(C1 + ((size_t)b * 100 + pp) * 32 + half * 16);
        *(short8*)&inTA[pos * 40 + half * 16]     = sp[0];
        *(short8*)&inTA[pos * 40 + half * 16 + 8] = sp[1];
    }
    const int m0 = wave * 32 + c16;
    const int m1 = m0 + 16;
    const int mc0 = (m0 < 100) ? m0 : 99, mc1 = (m1 < 100) ? m1 : 99;
    const int base0 = (mc0 / 10) * 12 + (mc0 % 10);
    const int base1 = (mc1 / 10) * 12 + (mc1 % 10);
    const int p0o = wave * 32 + quad * 4;
    f32x4 a00, a01, a10, a11;

// coalesced: linear global read, scattered LDS write
#define STAGE_W(wptr)                                                        \
    for (int i = t; i < 9216; i += 256) {                                    \
        float wv = (wptr)[i];                                                \
        int co = i / 288, rem = i - co * 288;                                \
        int ch = rem / 9, j = rem - ch * 9;                                  \
        Wt[j * 1280 + co * 40 + ch] = f2bf(wv);                              \
    }
#define CONV(src)                                                            \
    a00 = (f32x4){0.f,0.f,0.f,0.f}; a01 = (f32x4){0.f,0.f,0.f,0.f};          \
    a10 = (f32x4){0.f,0.f,0.f,0.f}; a11 = (f32x4){0.f,0.f,0.f,0.f};          \
    _Pragma("unroll")                                                        \
    for (int j = 0; j < 9; ++j) {                                            \
        const int offj = (j / 3) * 12 + (j % 3);                             \
        short8 af0 = *(const short8*)&(src)[(base0 + offj) * 40 + quad * 8]; \
        short8 af1 = *(const short8*)&(src)[(base1 + offj) * 40 + quad * 8]; \
        short8 bf0 = *(const short8*)&Wt[j * 1280 + c16 * 40 + quad * 8];    \
        short8 bf1 = *(const short8*)&Wt[j * 1280 + (16 + c16) * 40 + quad * 8]; \
        a00 = __builtin_amdgcn_mfma_f32_16x16x32_bf16(af0, bf0, a00, 0, 0, 0); \
        a01 = __builtin_amdgcn_mfma_f32_16x16x32_bf16(af0, bf1, a01, 0, 0, 0); \
        a10 = __builtin_amdgcn_mfma_f32_16x16x32_bf16(af1, bf0, a10, 0, 0, 0); \
        a11 = __builtin_amdgcn_mfma_f32_16x16x32_bf16(af1, bf1, a11, 0, 0, 0); \
    }
#define WRITE_RELU(dst)                                                      \
    _Pragma("unroll")                                                        \
    for (int r = 0; r < 4; ++r) {                                            \
        const int q0 = p0o + r, q1 = q0 + 16;                                \
        if (q0 < 100) {                                                      \
            int ps = (q0 / 10 + 1) * 12 + (q0 % 10) + 1;                     \
            (dst)[ps * 40 + c16]      = f2bf(fmaxf(a00[r], 0.f));            \
            (dst)[ps * 40 + 16 + c16] = f2bf(fmaxf(a01[r], 0.f));            \
        }                                                                    \
        if (q1 < 100) {                                                      \
            int ps = (q1 / 10 + 1) * 12 + (q1 % 10) + 1;                     \
            (dst)[ps * 40 + c16]      = f2bf(fmaxf(a10[r], 0.f));            \
            (dst)[ps * 40 + 16 + c16] = f2bf(fmaxf(a11[r], 0.f));            \
        }                                                                    \
    }

    STAGE_W(w2)
    __syncthreads();
    CONV(inTA)
    __syncthreads();
    WRITE_RELU(inTB)
    STAGE_W(w3)
    __syncthreads();
    CONV(inTB)
    __syncthreads();
    WRITE_RELU(inTA)
    STAGE_W(w4)
    __syncthreads();
    CONV(inTA)
    #pragma unroll
    for (int r = 0; r < 4; ++r) {
        const int q0 = p0o + r, q1 = q0 + 16;
        if (q0 < 100) {
            float rf = rfacL[q0];
            sig[c16 * 104 + q0]        = rf / (1.f + expf(-a00[r]));
            sig[(16 + c16) * 104 + q0] = rf / (1.f + expf(-a01[r]));
        }
        if (q1 < 100) {
            float rf = rfacL[q1];
            sig[c16 * 104 + q1]        = rf / (1.f + expf(-a10[r]));
            sig[(16 + c16) * 104 + q1] = rf / (1.f + expf(-a11[r]));
        }
    }
    __syncthreads();
    const int cc = t & 127, h = t >> 7;
    float accv[16];
    #pragma unroll
    for (int k = 0; k < 16; ++k) accv[k] = 0.f;
    const float* fp = feat + (size_t)cc * 100;
    for (int pp = 0; pp < 100; pp += 4) {
        float4 f4 = *(const float4*)&fp[pp];
        #pragma unroll
        for (int k = 0; k < 16; ++k) {
            const float* sg = &sig[(h + 2 * k) * 104 + pp];
            accv[k] += sg[0] * f4.x + sg[1] * f4.y + sg[2] * f4.z + sg[3] * f4.w;
        }
    }
    #pragma unroll
    for (int k = 0; k < 16; ++k)
        out[(size_t)b * 4096 + cc * 32 + (h + 2 * k)] = accv[k] * 0.01f;
#undef STAGE_W
#undef CONV
#undef WRITE_RELU
}

extern "C" void kernel_launch(void* const* d_in, const int* in_sizes, int n_in,
                              void* d_out, int out_size, void* d_ws, size_t ws_size,
                              hipStream_t stream) {
    (void)in_sizes; (void)n_in; (void)out_size; (void)ws_size;
    const float* sup    = (const float*)d_in[0];
    const float* qry    = (const float*)d_in[1];
    const float* td     = (const float*)d_in[2];
    const float* ln1_g  = (const float*)d_in[3];
    const float* ln1_b  = (const float*)d_in[4];
    const float* qkv_w  = (const float*)d_in[5];
    const float* qkv_b  = (const float*)d_in[6];
    const float* out_w  = (const float*)d_in[7];
    const float* out_b  = (const float*)d_in[8];
    const float* ln2_g  = (const float*)d_in[9];
    const float* ln2_b  = (const float*)d_in[10];
    const float* mlp_w1 = (const float*)d_in[11];
    const float* mlp_b1 = (const float*)d_in[12];
    const float* mlp_w2 = (const float*)d_in[13];
    const float* mlp_b2 = (const float*)d_in[14];
    const float* rg     = (const float*)d_in[15];
    const float* rb     = (const float*)d_in[16];
    const float* c1     = (const float*)d_in[17];
    const float* c2     = (const float*)d_in[18];
    const float* c3     = (const float*)d_in[19];
    const float* c4     = (const float*)d_in[20];
    float* out = (float*)d_out;

    float* ws    = (float*)d_ws;
    float* X     = ws;                       // 327680 f
    float* KEY0  = X + 327680;               // 2048 f
    float* RFAC  = KEY0 + 2048;              // 10000 f
    short* Hbf   = (short*)(RFAC + 10000);   // 327680 shorts (2560x128 bf16)
    short* Qbf   = Hbf + 327680;             // 327680
    short* Kbf   = Qbf + 327680;             // 327680
    short* VTb   = Kbf + 327680;             // 327680
    short* C1    = VTb + 327680;             // 320000 (100*100*32)
    float* PARTG = (float*)(C1 + 320000);    // 8*2560*128 floats (PART aliases)
    float* PART  = PARTG;

    const int SG = (SEQ + 7) / 8;            // 315
    const int MT = (SEQ + 63) / 64;          // 40

    concat_ln_kernel<<<SEQ, 64, 0, stream>>>(td, sup, ln1_g, ln1_b, X, Hbf);
    // ---- layer 0 (full) ----
    qkv_mfma_kernel<<<dim3(MT, 6), 256, 0, stream>>>(
        Hbf, qkv_w, qkv_b, Qbf, Kbf, VTb, MT);
    attn_kernel<<<dim3(MT, 8, 2), 256, 0, stream>>>(Qbf, Kbf, VTb, PART);
    proj_merge_ln_kernel<<<SG, 512, 0, stream>>>(
        PART, out_w, out_b, X, X, Hbf, ln2_g, ln2_b, SEQ);
    mlp_fused_kernel<<<dim3(MT, 8), 256, 0, stream>>>(
        Hbf, mlp_w1, mlp_b1, mlp_w2, PARTG);
    combine_ln_kernel<<<SG, 512, 0, stream>>>(
        PARTG, mlp_b2, X, X, Hbf, ln1_g + 128, ln1_b + 128, 16, KEY0);
    // ---- layer 1 (only rows 0..15 of output are consumed via key0) ----
    qkv_mfma_kernel<<<dim3(MT, 6), 256, 0, stream>>>(
        Hbf, qkv_w + (size_t)128 * 384, qkv_b + 384, Qbf, Kbf, VTb, 1);
    attn_kernel<<<dim3(1, 8, 2), 256, 0, stream>>>(Qbf, Kbf, VTb, PART);
    pml16_kernel<<<8, 512, 0, stream>>>(
        PART, out_w + 128 * 128, out_b + 128, ln2_g + 128, ln2_b + 128,
        mlp_w1 + (size_t)128 * 512, mlp_b1 + 512, mlp_w2 + (size_t)512 * 128,
        mlp_b2 + 128, X, KEY0);
    // ---- conv tail ----
    region_conv1_kernel<<<100, 256, 0, stream>>>(sup, qry, KEY0, rg, rb, c1, C1, RFAC);
    conv234_pool_kernel<<<100, 256, 0, stream>>>(C1, c2, c3, c4, sup, qry, RFAC, out);
}

// Round 9
// 262.412 us; speedup vs baseline: 1.1592x; 1.1592x over previous
//
#include <hip/hip_runtime.h>
#include <math.h>

#define SEQ 2516
#define SEQP 2520
#define SEQP2 2560
#define CDIM 128

typedef __attribute__((ext_vector_type(8))) short short8;
typedef __attribute__((ext_vector_type(4))) float f32x4;

__device__ __forceinline__ float gelu_exact(float x) {
    return x * 0.5f * (1.0f + erff(x * 0.7071067811865475f));
}
__device__ __forceinline__ float fexp2(float x) { return __builtin_amdgcn_exp2f(x); }
__device__ __forceinline__ short f2bf(float f) {     // fp32 -> bf16 RNE
    unsigned u = __float_as_uint(f);
    unsigned r = 0x7fffu + ((u >> 16) & 1u);
    return (short)((u + r) >> 16);
}
__device__ __forceinline__ short f2bf_trunc(float f) {   // for P (e>=0): 1 op
    return (short)(__float_as_uint(f) >> 16);
}

// ------------- concat + LN1(layer0): one wave per row; H stored bf16 ------------
__global__ __launch_bounds__(64) void concat_ln_kernel(
    const float* __restrict__ td, const float* __restrict__ sup,
    const float* __restrict__ g, const float* __restrict__ b,
    float* __restrict__ X, short* __restrict__ Hbf) {
    const int row = blockIdx.x;
    const int t = threadIdx.x;
    float x0, x1;
    if (row < 16) {
        x0 = td[row * 128 + t];
        x1 = td[row * 128 + 64 + t];
    } else {
        int r = row - 16;
        int n = r / 100, p = r - n * 100;
        x0 = sup[n * 12800 + t * 100 + p];
        x1 = sup[n * 12800 + (t + 64) * 100 + p];
    }
    X[row * 128 + t] = x0;
    X[row * 128 + 64 + t] = x1;
    float s = x0 + x1;
    for (int off = 32; off > 0; off >>= 1) s += __shfl_down(s, off);
    float mean = __shfl(s, 0) * (1.f / 128.f);
    float d0 = x0 - mean, d1 = x1 - mean;
    float v = d0 * d0 + d1 * d1;
    for (int off = 32; off > 0; off >>= 1) v += __shfl_down(v, off);
    float var = __shfl(v, 0) * (1.f / 128.f);
    float rstd = rsqrtf(var + 1e-5f);
    Hbf[row * 128 + t]      = f2bf(d0 * rstd * g[t] + b[t]);
    Hbf[row * 128 + 64 + t] = f2bf(d1 * rstd * g[t + 64] + b[t + 64]);
}

// ---- qkv MFMA GEMM: A is pre-converted bf16 (Hbf). Writes Q/K bf16, V^T bf16 ---
__global__ __launch_bounds__(256) void qkv_mfma_kernel(
    const short* __restrict__ A, const float* __restrict__ W,
    const float* __restrict__ bias,
    short* __restrict__ Qbf, short* __restrict__ Kbf, short* __restrict__ VTb,
    int q_mt) {
    if (blockIdx.y < 2 && (int)blockIdx.x >= q_mt) return;   // uniform: whole block
    __shared__ __align__(16) short Wt[64 * 136];   // 17.4 KB
    const int t = threadIdx.x;
    const int wave = t >> 6, lane = t & 63;
    const int quad = lane >> 4, c16 = lane & 15;
    const int m0 = blockIdx.x * 64;
    const int n0 = blockIdx.y * 64;
    const float SC = 0.25f * 1.4426950408889634f;   // folded into Q
    #pragma unroll
    for (int pass = 0; pass < 4; ++pass) {
        int idx = t + pass * 256;
        int n = idx & 63, kc = idx >> 6;
        short8 wv;
        #pragma unroll
        for (int j = 0; j < 8; ++j)
            wv[j] = f2bf(W[(size_t)(kc * 8 + j) * 384 + n0 + n]);
        *(short8*)&Wt[n * 136 + kc * 8] = wv;
    }
    __syncthreads();
    const int am = m0 + wave * 16 + c16;
    f32x4 acc[4];
    #pragma unroll
    for (int i = 0; i < 4; ++i) acc[i] = (f32x4){0.f, 0.f, 0.f, 0.f};
    #pragma unroll
    for (int kk = 0; kk < 4; ++kk) {
        short8 af = *(const short8*)(A + (size_t)am * 128 + kk * 32 + quad * 8);
        #pragma unroll
        for (int ns = 0; ns < 4; ++ns) {
            short8 wf = *(const short8*)&Wt[(ns * 16 + c16) * 136 + kk * 32 + quad * 8];
            acc[ns] = __builtin_amdgcn_mfma_f32_16x16x32_bf16(af, wf, acc[ns], 0, 0, 0);
        }
    }
    const int region = __builtin_amdgcn_readfirstlane(n0 >> 7);  // 0 Q, 1 K, 2 V
    #pragma unroll
    for (int ns = 0; ns < 4; ++ns) {
        const int n = n0 + ns * 16 + c16;
        float bv = bias[n];
        #pragma unroll
        for (int r = 0; r < 4; ++r) {
            const int row = m0 + wave * 16 + quad * 4 + r;
            float v = acc[ns][r] + bv;
            if (region == 0)      Qbf[(size_t)row * 128 + n] = f2bf(v * SC);
            else if (region == 1) Kbf[(size_t)row * 128 + (n - 128)] = f2bf(v);
            else                  VTb[(size_t)(n - 256) * SEQP2 + row] = f2bf(v);
        }
    }
}

// ---- attention: bf16 MFMA flash, pre-converted inputs, split-K=2 ---------------
__global__ __launch_bounds__(128) void attn_kernel(
    const short* __restrict__ Qbf, const short* __restrict__ Kbf,
    const short* __restrict__ VTb, float* __restrict__ PART) {
    __shared__ __align__(16) short sKs[9600];  // Ks 128*24 | Vt 16*136 | P 2*16*136
    short* Ks = sKs;
    short* Vt = sKs + 3072;
    const int t = threadIdx.x;
    const int wave = t >> 6, lane = t & 63;
    const int quad = lane >> 4, c16 = lane & 15;
    short* Pw = sKs + 3072 + 2176 + wave * 16 * 136;
    const int head = blockIdx.y, z = blockIdx.z;
    const int qb = blockIdx.x * 32 + wave * 16;

    short8 qf;
    #pragma unroll
    for (int i = 0; i < 8; ++i) qf[i] = 0;
    if (quad < 2)
        qf = *(const short8*)(Qbf + (size_t)(qb + c16) * 128 + head * 16 + quad * 8);
    f32x4 oacc = {0.f, 0.f, 0.f, 0.f};
    float m_[4] = {-INFINITY, -INFINITY, -INFINITY, -INFINITY};
    float l_[4] = {0.f, 0.f, 0.f, 0.f};

    const int vdim = t >> 3, vseg = t & 7;
    const int tA = z * 10, tB = z ? 20 : 10;
    for (int ti = tA; ti < tB; ++ti) {
        const int tile0 = ti * 128;
        if (ti != tA) __syncthreads();
        {
            const short8* kp = (const short8*)(Kbf + (size_t)(tile0 + t) * 128 + head * 16);
            *(short8*)&Ks[t * 24]     = kp[0];
            *(short8*)&Ks[t * 24 + 8] = kp[1];
            const short8* vp = (const short8*)(VTb + (size_t)(head * 16 + vdim) * SEQP2 + tile0 + vseg * 16);
            *(short8*)&Vt[vdim * 136 + vseg * 16]     = vp[0];
            *(short8*)&Vt[vdim * 136 + vseg * 16 + 8] = vp[1];
        }
        __syncthreads();

        f32x4 sA[4], sB[4];
        #pragma unroll
        for (int st = 0; st < 4; ++st) {
            const int k0 = st * 32;
            short8 kfA, kfB;
            #pragma unroll
            for (int i = 0; i < 8; ++i) { kfA[i] = 0; kfB[i] = 0; }
            if (quad < 2) {
                kfA = *(const short8*)&Ks[(k0 + c16) * 24 + quad * 8];
                kfB = *(const short8*)&Ks[(k0 + 16 + c16) * 24 + quad * 8];
            }
            f32x4 zz = {0.f, 0.f, 0.f, 0.f};
            sA[st] = __builtin_amdgcn_mfma_f32_16x16x32_bf16(qf, kfA, zz, 0, 0, 0);
            sB[st] = __builtin_amdgcn_mfma_f32_16x16x32_bf16(qf, kfB, zz, 0, 0, 0);
            const bool badA = (tile0 + k0 + c16) >= SEQ;
            const bool badB = (tile0 + k0 + 16 + c16) >= SEQ;
            if (badA) { sA[st][0] = -1e30f; sA[st][1] = -1e30f; sA[st][2] = -1e30f; sA[st][3] = -1e30f; }
            if (badB) { sB[st][0] = -1e30f; sB[st][1] = -1e30f; sB[st][2] = -1e30f; sB[st][3] = -1e30f; }
        }
        #pragma unroll
        for (int r = 0; r < 4; ++r) {
            float v = fmaxf(sA[0][r], sB[0][r]);
            #pragma unroll
            for (int st = 1; st < 4; ++st) v = fmaxf(v, fmaxf(sA[st][r], sB[st][r]));
            v = fmaxf(v, __shfl_xor(v, 1));
            v = fmaxf(v, __shfl_xor(v, 2));
            v = fmaxf(v, __shfl_xor(v, 4));
            v = fmaxf(v, __shfl_xor(v, 8));
            float nm = fmaxf(m_[r], v);
            float corr = fexp2(m_[r] - nm);
            m_[r] = nm;
            oacc[r] *= corr;
            l_[r] *= corr;
        }
        #pragma unroll
        for (int st = 0; st < 4; ++st) {
            #pragma unroll
            for (int r = 0; r < 4; ++r) {
                float eA = fexp2(sA[st][r] - m_[r]);
                float eB = fexp2(sB[st][r] - m_[r]);
                l_[r] += eA + eB;
                Pw[(quad * 4 + r) * 136 + st * 32 + c16]      = f2bf_trunc(eA);
                Pw[(quad * 4 + r) * 136 + st * 32 + 16 + c16] = f2bf_trunc(eB);
            }
        }
        #pragma unroll
        for (int st = 0; st < 4; ++st) {
            short8 pf = *(const short8*)&Pw[c16 * 136 + st * 32 + quad * 8];
            short8 vf = *(const short8*)&Vt[c16 * 136 + st * 32 + quad * 8];
            oacc = __builtin_amdgcn_mfma_f32_16x16x32_bf16(pf, vf, oacc, 0, 0, 0);
        }
    }
    #pragma unroll
    for (int r = 0; r < 4; ++r) {
        float lr = l_[r];
        lr += __shfl_xor(lr, 1);
        lr += __shfl_xor(lr, 2);
        lr += __shfl_xor(lr, 4);
        lr += __shfl_xor(lr, 8);
        const int qrow = qb + quad * 4 + r;
        if (qrow < SEQ) {
            float* dst = PART + ((size_t)(z * 8 + head) * SEQP + qrow) * 20;
            dst[c16] = oacc[r];
            if (c16 == 0) { dst[16] = m_[r]; dst[17] = lr; }
        }
    }
}

// ---- proj GEMM fused with attn 2-way split merge + residual + row-LN -----------
__global__ __launch_bounds__(512) void proj_merge_ln_kernel(
    const float* __restrict__ PART, const float* __restrict__ W,
    const float* __restrict__ bias, const float* __restrict__ R,
    float* __restrict__ C, short* __restrict__ Hbf,
    const float* __restrict__ g, const float* __restrict__ bb, int M) {
    __shared__ float ln[8][130];
    const int t = threadIdx.x;
    const int c = t & 127;
    const int grp = __builtin_amdgcn_readfirstlane(t >> 7);
    const int r0 = blockIdx.x * 8 + grp * 2;
    float acc0 = 0.f, acc1 = 0.f;
    #pragma unroll
    for (int h = 0; h < 8; ++h) {
        const float* p0a = PART + ((size_t)h * SEQP + r0) * 20;
        const float* p1a = PART + ((size_t)(8 + h) * SEQP + r0) * 20;
        const float* p0b = p0a + 20;
        const float* p1b = p1a + 20;
        float m0 = p0a[16], l0 = p0a[17], m1 = p1a[16], l1 = p1a[17];
        float Ma = fmaxf(m0, m1);
        float w0 = fexp2(m0 - Ma), w1 = fexp2(m1 - Ma);
        float inva = 1.f / fmaf(l0, w0, l1 * w1);
        float c0a = w0 * inva, c1a = w1 * inva;
        m0 = p0b[16]; l0 = p0b[17]; m1 = p1b[16]; l1 = p1b[17];
        float Mb = fmaxf(m0, m1);
        w0 = fexp2(m0 - Mb); w1 = fexp2(m1 - Mb);
        float invb = 1.f / fmaf(l0, w0, l1 * w1);
        float c0b = w0 * invb, c1b = w1 * invb;
        #pragma unroll
        for (int kk = 0; kk < 4; ++kk) {
            const int k0 = h * 16 + kk * 4;
            float w_0 = W[(size_t)(k0 + 0) * 128 + c];
            float w_1 = W[(size_t)(k0 + 1) * 128 + c];
            float w_2 = W[(size_t)(k0 + 2) * 128 + c];
            float w_3 = W[(size_t)(k0 + 3) * 128 + c];
            float4 x0 = *(const float4*)&p0a[kk * 4];
            float4 y0 = *(const float4*)&p1a[kk * 4];
            float4 x1 = *(const float4*)&p0b[kk * 4];
            float4 y1 = *(const float4*)&p1b[kk * 4];
            float a00 = x0.x * c0a + y0.x * c1a;
            float a01 = x0.y * c0a + y0.y * c1a;
            float a02 = x0.z * c0a + y0.z * c1a;
            float a03 = x0.w * c0a + y0.w * c1a;
            float a10 = x1.x * c0b + y1.x * c1b;
            float a11 = x1.y * c0b + y1.y * c1b;
            float a12 = x1.z * c0b + y1.z * c1b;
            float a13 = x1.w * c0b + y1.w * c1b;
            acc0 = fmaf(a00, w_0, acc0); acc0 = fmaf(a01, w_1, acc0);
            acc0 = fmaf(a02, w_2, acc0); acc0 = fmaf(a03, w_3, acc0);
            acc1 = fmaf(a10, w_0, acc1); acc1 = fmaf(a11, w_1, acc1);
            acc1 = fmaf(a12, w_2, acc1); acc1 = fmaf(a13, w_3, acc1);
        }
    }
    float bv = bias[c];
    float v0 = acc0 + bv + R[(size_t)(r0 + 0) * 128 + c];
    float v1 = acc1 + bv + R[(size_t)(r0 + 1) * 128 + c];
    ln[grp * 2 + 0][c] = v0;
    ln[grp * 2 + 1][c] = v1;
    if (r0 + 0 < M) C[(size_t)(r0 + 0) * 128 + c] = v0;
    if (r0 + 1 < M) C[(size_t)(r0 + 1) * 128 + c] = v1;
    __syncthreads();
    const int wv = t >> 6, l = t & 63;
    float x0 = ln[wv][l], x1 = ln[wv][l + 64];
    float s = x0 + x1;
    for (int off = 32; off > 0; off >>= 1) s += __shfl_down(s, off);
    float mean = __shfl(s, 0) * (1.f / 128.f);
    float d0 = x0 - mean, d1 = x1 - mean;
    float vv = d0 * d0 + d1 * d1;
    for (int off = 32; off > 0; off >>= 1) vv += __shfl_down(vv, off);
    float var = __shfl(vv, 0) * (1.f / 128.f);
    float rstd = rsqrtf(var + 1e-5f);
    const int hrow = blockIdx.x * 8 + wv;
    Hbf[(size_t)hrow * 128 + l]      = f2bf(d0 * rstd * g[l] + bb[l]);
    Hbf[(size_t)hrow * 128 + 64 + l] = f2bf(d1 * rstd * g[l + 64] + bb[l + 64]);
}

// ---- FUSED mlp1+mlp2-kpart: grid (M-tiles, 8 kz); A is bf16 (Hbf) --------------
__global__ __launch_bounds__(256) void mlp_fused_kernel(
    const short* __restrict__ A, const float* __restrict__ W1,
    const float* __restrict__ b1, const float* __restrict__ W2,
    float* __restrict__ PARTG) {
    __shared__ __align__(16) short W1t[64 * 136];   // 17.4 KB
    __shared__ __align__(16) short W2t[128 * 72];   // 18.4 KB
    __shared__ __align__(16) short Ct[4 * 16 * 72]; //  9.2 KB (per-wave 16x72)
    const int t = threadIdx.x;
    const int wave = t >> 6, lane = t & 63;
    const int quad = lane >> 4, c16 = lane & 15;
    const int m0 = blockIdx.x * 64;
    const int kz = blockIdx.y;
    const int n0 = kz * 64;
    #pragma unroll
    for (int pass = 0; pass < 4; ++pass) {
        int idx = t + pass * 256;
        int n = idx & 63, kc = idx >> 6;
        short8 wv;
        #pragma unroll
        for (int j = 0; j < 8; ++j)
            wv[j] = f2bf(W1[(size_t)(kc * 8 + j) * 512 + n0 + n]);
        *(short8*)&W1t[n * 136 + kc * 8] = wv;
    }
    {
        const int n = t & 127, half = t >> 7;
        #pragma unroll
        for (int c = 0; c < 4; ++c) {
            short8 wv;
            #pragma unroll
            for (int j = 0; j < 8; ++j)
                wv[j] = f2bf(W2[(size_t)(n0 + half * 32 + c * 8 + j) * 128 + n]);
            *(short8*)&W2t[n * 72 + half * 32 + c * 8] = wv;
        }
    }
    __syncthreads();
    const int am = m0 + wave * 16 + c16;
    f32x4 acc1[4];
    #pragma unroll
    for (int i = 0; i < 4; ++i) acc1[i] = (f32x4){0.f, 0.f, 0.f, 0.f};
    #pragma unroll
    for (int kk = 0; kk < 4; ++kk) {
        short8 af = *(const short8*)(A + (size_t)am * 128 + kk * 32 + quad * 8);
        #pragma unroll
        for (int ns = 0; ns < 4; ++ns) {
            short8 wf = *(const short8*)&W1t[(ns * 16 + c16) * 136 + kk * 32 + quad * 8];
            acc1[ns] = __builtin_amdgcn_mfma_f32_16x16x32_bf16(af, wf, acc1[ns], 0, 0, 0);
        }
    }
    short* Cw = Ct + wave * 16 * 72;
    #pragma unroll
    for (int ns = 0; ns < 4; ++ns) {
        float bv = b1[n0 + ns * 16 + c16];
        #pragma unroll
        for (int r = 0; r < 4; ++r)
            Cw[(quad * 4 + r) * 72 + ns * 16 + c16] = f2bf(gelu_exact(acc1[ns][r] + bv));
    }
    f32x4 acc2[8];
    #pragma unroll
    for (int i = 0; i < 8; ++i) acc2[i] = (f32x4){0.f, 0.f, 0.f, 0.f};
    #pragma unroll
    for (int kk = 0; kk < 2; ++kk) {
        short8 af2 = *(const short8*)&Cw[c16 * 72 + kk * 32 + quad * 8];
        #pragma unroll
        for (int ns = 0; ns < 8; ++ns) {
            short8 wf = *(const short8*)&W2t[(ns * 16 + c16) * 72 + kk * 32 + quad * 8];
            acc2[ns] = __builtin_amdgcn_mfma_f32_16x16x32_bf16(af2, wf, acc2[ns], 0, 0, 0);
        }
    }
    float* dst = PARTG + (size_t)kz * SEQP2 * 128;
    #pragma unroll
    for (int ns = 0; ns < 8; ++ns) {
        #pragma unroll
        for (int r = 0; r < 4; ++r) {
            const int row = m0 + wave * 16 + quad * 4 + r;
            dst[(size_t)row * 128 + ns * 16 + c16] = acc2[ns][r];
        }
    }
}

// ---- combine 8 K-split partials + bias + residual + row-LN (+optional zero) ----
__global__ __launch_bounds__(512) void combine_ln_kernel(
    const float* __restrict__ PARTG, const float* __restrict__ bias,
    const float* __restrict__ R, float* __restrict__ C, short* __restrict__ Hbf,
    const float* __restrict__ g, const float* __restrict__ bb, int M,
    float* __restrict__ zk) {
    __shared__ float ln[8][130];
    const int t = threadIdx.x;
    if (zk != nullptr && blockIdx.x == 0) {
        #pragma unroll
        for (int i = 0; i < 4; ++i) zk[t + i * 512] = 0.f;
    }
    const int c = t & 127;
    const int grp = __builtin_amdgcn_readfirstlane(t >> 7);
    const int r0 = blockIdx.x * 8 + grp * 2;
    #pragma unroll
    for (int i = 0; i < 2; ++i) {
        const int row = r0 + i;
        float v = bias[c] + R[(size_t)row * 128 + c];
        #pragma unroll
        for (int kz = 0; kz < 8; ++kz)
            v += PARTG[(size_t)kz * SEQP2 * 128 + (size_t)row * 128 + c];
        ln[grp * 2 + i][c] = v;
        if (row < M) C[(size_t)row * 128 + c] = v;
    }
    __syncthreads();
    const int wv = t >> 6, l = t & 63;
    float x0 = ln[wv][l], x1 = ln[wv][l + 64];
    float s = x0 + x1;
    for (int off = 32; off > 0; off >>= 1) s += __shfl_down(s, off);
    float mean = __shfl(s, 0) * (1.f / 128.f);
    float d0 = x0 - mean, d1 = x1 - mean;
    float vv = d0 * d0 + d1 * d1;
    for (int off = 32; off > 0; off >>= 1) vv += __shfl_down(vv, off);
    float var = __shfl(vv, 0) * (1.f / 128.f);
    float rstd = rsqrtf(var + 1e-5f);
    const int hrow = blockIdx.x * 8 + wv;
    Hbf[(size_t)hrow * 128 + l]      = f2bf(d0 * rstd * g[l] + bb[l]);
    Hbf[(size_t)hrow * 128 + 64 + l] = f2bf(d1 * rstd * g[l + 64] + bb[l + 64]);
}

// ---- LAYER-1 TAIL: proj+merge+LN for 16 rows (redundant per block) + MLP kz-slice
__global__ __launch_bounds__(512) void pml16_kernel(
    const float* __restrict__ PART, const float* __restrict__ Wo,
    const float* __restrict__ ob, const float* __restrict__ g2,
    const float* __restrict__ bl2, const float* __restrict__ W1,
    const float* __restrict__ b1, const float* __restrict__ W2,
    const float* __restrict__ b2, const float* __restrict__ X,
    float* __restrict__ KEY0) {
    __shared__ __align__(16) char SMEM[4352 + 38912];
    short* hA   = (short*)SMEM;                  // 16 x 136 bf16 (persistent)
    char*  U    = SMEM + 4352;                   // union region
    float* PARTL = (float*)U;                    // 5120 f  [sh16][row16][20]
    float* coefL = PARTL + 5120;                 // 256 f   [row16][h8][2]
    float* xpL   = coefL + 256;                  // 16*130 f
    short* W1t  = (short*)U;                     // 64*136
    short* W2t  = W1t + 8704;                    // 128*72
    short* Ct   = W2t + 9216;                    // 16*72
    const int t = threadIdx.x;
    const int kz = blockIdx.x;

    for (int i = t; i < 5120; i += 512) {
        int sh = i / 320, rem = i - sh * 320;
        PARTL[i] = PART[((size_t)sh * SEQP) * 20 + rem];
    }
    __syncthreads();
    if (t < 128) {
        int row = t >> 3, h = t & 7;
        float ma = PARTL[h * 320 + row * 20 + 16];
        float la = PARTL[h * 320 + row * 20 + 17];
        float mb = PARTL[(8 + h) * 320 + row * 20 + 16];
        float lb = PARTL[(8 + h) * 320 + row * 20 + 17];
        float Mx = fmaxf(ma, mb);
        float w0 = fexp2(ma - Mx), w1 = fexp2(mb - Mx);
        float inv = 1.f / fmaf(la, w0, lb * w1);
        coefL[row * 16 + h * 2]     = w0 * inv;
        coefL[row * 16 + h * 2 + 1] = w1 * inv;
    }
    __syncthreads();
    const int c = t & 127;
    const int grp = t >> 7;
    float xv[4] = {0.f, 0.f, 0.f, 0.f};
    for (int h = 0; h < 8; ++h) {
        float c0v[4], c1v[4];
        #pragma unroll
        for (int i = 0; i < 4; ++i) {
            int row = grp * 4 + i;
            c0v[i] = coefL[row * 16 + h * 2];
            c1v[i] = coefL[row * 16 + h * 2 + 1];
        }
        #pragma unroll
        for (int d = 0; d < 16; ++d) {
            float w = Wo[(size_t)(h * 16 + d) * 128 + c];
            #pragma unroll
            for (int i = 0; i < 4; ++i) {
                int row = grp * 4 + i;
                float a = PARTL[h * 320 + row * 20 + d] * c0v[i]
                        + PARTL[(8 + h) * 320 + row * 20 + d] * c1v[i];
                xv[i] = fmaf(a, w, xv[i]);
            }
        }
    }
    #pragma unroll
    for (int i = 0; i < 4; ++i) {
        int row = grp * 4 + i;
        float v = xv[i] + ob[c] + X[(size_t)row * 128 + c];
        xpL[row * 130 + c] = v;
        if (kz == 0) atomicAdd(&KEY0[row * 128 + c], v + b2[c]);
    }
    __syncthreads();
    {
        const int wv6 = t >> 6, l = t & 63;
        #pragma unroll
        for (int rr = 0; rr < 2; ++rr) {
            int row = wv6 * 2 + rr;
            float x0 = xpL[row * 130 + l], x1 = xpL[row * 130 + 64 + l];
            float s = x0 + x1;
            s += __shfl_xor(s, 1); s += __shfl_xor(s, 2); s += __shfl_xor(s, 4);
            s += __shfl_xor(s, 8); s += __shfl_xor(s, 16); s += __shfl_xor(s, 32);
            float mean = s * (1.f / 128.f);
            float d0 = x0 - mean, d1 = x1 - mean;
            float vv = d0 * d0 + d1 * d1;
            vv += __shfl_xor(vv, 1); vv += __shfl_xor(vv, 2); vv += __shfl_xor(vv, 4);
            vv += __shfl_xor(vv, 8); vv += __shfl_xor(vv, 16); vv += __shfl_xor(vv, 32);
            float rstd = rsqrtf(vv * (1.f / 128.f) + 1e-5f);
            hA[row * 136 + l]      = f2bf(d0 * rstd * g2[l] + bl2[l]);
            hA[row * 136 + 64 + l] = f2bf(d1 * rstd * g2[64 + l] + bl2[64 + l]);
        }
    }
    __syncthreads();   // xpL/PARTL dead; reuse U for weights
    for (int idx = t; idx < 1024; idx += 512) {
        int n = idx & 63, kc = idx >> 6;
        short8 wv;
        #pragma unroll
        for (int j = 0; j < 8; ++j)
            wv[j] = f2bf(W1[(size_t)(kc * 8 + j) * 512 + kz * 64 + n]);
        *(short8*)&W1t[n * 136 + kc * 8] = wv;
    }
    for (int idx = t; idx < 1024; idx += 512) {
        int n = idx & 127, kc = idx >> 7;
        short8 wv;
        #pragma unroll
        for (int j = 0; j < 8; ++j)
            wv[j] = f2bf(W2[(size_t)(kz * 64 + kc * 8 + j) * 128 + n]);
        *(short8*)&W2t[n * 72 + kc * 8] = wv;
    }
    __syncthreads();
    if (t < 64) {
        const int quad = t >> 4, c16 = t & 15;
        f32x4 acc1[4];
        #pragma unroll
        for (int i = 0; i < 4; ++i) acc1[i] = (f32x4){0.f, 0.f, 0.f, 0.f};
        #pragma unroll
        for (int kk = 0; kk < 4; ++kk) {
            short8 af = *(const short8*)&hA[c16 * 136 + kk * 32 + quad * 8];
            #pragma unroll
            for (int ns = 0; ns < 4; ++ns) {
                short8 wf = *(const short8*)&W1t[(ns * 16 + c16) * 136 + kk * 32 + quad * 8];
                acc1[ns] = __builtin_amdgcn_mfma_f32_16x16x32_bf16(af, wf, acc1[ns], 0, 0, 0);
            }
        }
        #pragma unroll
        for (int ns = 0; ns < 4; ++ns) {
            float bv = b1[kz * 64 + ns * 16 + c16];
            #pragma unroll
            for (int r = 0; r < 4; ++r)
                Ct[(quad * 4 + r) * 72 + ns * 16 + c16] = f2bf(gelu_exact(acc1[ns][r] + bv));
        }
        f32x4 acc2[8];
        #pragma unroll
        for (int i = 0; i < 8; ++i) acc2[i] = (f32x4){0.f, 0.f, 0.f, 0.f};
        #pragma unroll
        for (int kk = 0; kk < 2; ++kk) {
            short8 af2 = *(const short8*)&Ct[c16 * 72 + kk * 32 + quad * 8];
            #pragma unroll
            for (int ns = 0; ns < 8; ++ns) {
                short8 wf = *(const short8*)&W2t[(ns * 16 + c16) * 72 + kk * 32 + quad * 8];
                acc2[ns] = __builtin_amdgcn_mfma_f32_16x16x32_bf16(af2, wf, acc2[ns], 0, 0, 0);
            }
        }
        #pragma unroll
        for (int ns = 0; ns < 8; ++ns) {
            #pragma unroll
            for (int r = 0; r < 4; ++r)
                atomicAdd(&KEY0[(quad * 4 + r) * 128 + ns * 16 + c16], acc2[ns][r]);
        }
    }
}

// ---- region + stats + conv1-MFMA fused (grid 100) ------------------------------
__global__ __launch_bounds__(256) void region_conv1_kernel(
    const float* __restrict__ sup, const float* __restrict__ qry,
    const float* __restrict__ KEY0, const float* __restrict__ rg,
    const float* __restrict__ rb, const float* __restrict__ w,
    short* __restrict__ C1, float* __restrict__ RFAC) {
    __shared__ float key0L[2048];
    __shared__ float rfacL[104], MEANL[104], RSTDL[104];
    __shared__ __align__(16) short inT[144 * 136];  // 39.2 KB
    __shared__ __align__(16) short Wt[32 * 136];    //  8.7 KB
    const int b = blockIdx.x;
    const int t = threadIdx.x;
    const int wave = t >> 6, lane = t & 63;
    const int quad = lane >> 4, c16 = lane & 15;
    const float* feat = (b < 25) ? (sup + (size_t)b * 12800) : (qry + (size_t)(b - 25) * 12800);
    for (int i = t; i < 2048; i += 256) key0L[i] = KEY0[i];
    for (int i = t; i < 2448; i += 256) {    // zero inT (halo must stay 0)
        short8 z;
        #pragma unroll
        for (int j = 0; j < 8; ++j) z[j] = 0;
        *(short8*)&inT[i * 8] = z;
    }
    __syncthreads();
    if (t < 100) {
        float dots[16];
        #pragma unroll
        for (int mm = 0; mm < 16; ++mm) dots[mm] = 0.f;
        float s = 0.f, ss = 0.f;
        for (int c = 0; c < 128; ++c) {
            float f = feat[c * 100 + t];
            s += f; ss = fmaf(f, f, ss);
            #pragma unroll
            for (int mm = 0; mm < 16; ++mm) dots[mm] = fmaf(f, key0L[mm * 128 + c], dots[mm]);
        }
        float m16 = 0.f;
        #pragma unroll
        for (int mm = 0; mm < 16; ++mm) m16 += 1.f / (1.f + expf(-dots[mm] * (1.f / 128.f)));
        float r = m16 * (1.f / 16.f) + 1.f;
        rfacL[t] = r;
        RFAC[b * 100 + t] = r;
        float mr = s * (1.f / 128.f);
        float vr = ss * (1.f / 128.f) - mr * mr;
        MEANL[t] = mr * r;
        RSTDL[t] = rsqrtf(vr * r * r + 1e-6f);
    }
    __syncthreads();
    for (int i = t; i < 12800; i += 256) {
        int cc = i / 100, p = i - cc * 100;
        float v = feat[i] * rfacL[p];
        float lnv = (v - MEANL[p]) * RSTDL[p] * rg[cc] + rb[cc];
        int pos = (p / 10 + 1) * 12 + (p % 10) + 1;
        inT[pos * 136 + cc] = f2bf(lnv);
    }
    const int m0 = wave * 32 + c16;
    const int m1 = m0 + 16;
    const int mc0 = (m0 < 100) ? m0 : 99, mc1 = (m1 < 100) ? m1 : 99;
    const int base0 = (mc0 / 10) * 12 + (mc0 % 10);
    const int base1 = (mc1 / 10) * 12 + (mc1 % 10);
    f32x4 a00 = {0.f,0.f,0.f,0.f}, a01 = {0.f,0.f,0.f,0.f};
    f32x4 a10 = {0.f,0.f,0.f,0.f}, a11 = {0.f,0.f,0.f,0.f};
    for (int j = 0; j < 9; ++j) {
        __syncthreads();
        for (int i = t; i < 4096; i += 256) {
            int co = i >> 7, cin = i & 127;
            Wt[co * 136 + cin] = f2bf(w[(size_t)(co * 128 + cin) * 9 + j]);
        }
        __syncthreads();
        const int offj = (j / 3) * 12 + (j % 3);
        #pragma unroll
        for (int kk = 0; kk < 4; ++kk) {
            short8 af0 = *(const short8*)&inT[(base0 + offj) * 136 + kk * 32 + quad * 8];
            short8 af1 = *(const short8*)&inT[(base1 + offj) * 136 + kk * 32 + quad * 8];
            short8 bf0 = *(const short8*)&Wt[c16 * 136 + kk * 32 + quad * 8];
            short8 bf1 = *(const short8*)&Wt[(16 + c16) * 136 + kk * 32 + quad * 8];
            a00 = __builtin_amdgcn_mfma_f32_16x16x32_bf16(af0, bf0, a00, 0, 0, 0);
            a01 = __builtin_amdgcn_mfma_f32_16x16x32_bf16(af0, bf1, a01, 0, 0, 0);
            a10 = __builtin_amdgcn_mfma_f32_16x16x32_bf16(af1, bf0, a10, 0, 0, 0);
            a11 = __builtin_amdgcn_mfma_f32_16x16x32_bf16(af1, bf1, a11, 0, 0, 0);
        }
    }
    #pragma unroll
    for (int r = 0; r < 4; ++r) {
        const int p0 = wave * 32 + quad * 4 + r;
        const int p1 = p0 + 16;
        if (p0 < 100) {
            C1[((size_t)b * 100 + p0) * 32 + c16]      = f2bf(fmaxf(a00[r], 0.f));
            C1[((size_t)b * 100 + p0) * 32 + 16 + c16] = f2bf(fmaxf(a01[r], 0.f));
        }
        if (p1 < 100) {
            C1[((size_t)b * 100 + p1) * 32 + c16]      = f2bf(fmaxf(a10[r], 0.f));
            C1[((size_t)b * 100 + p1) * 32 + 16 + c16] = f2bf(fmaxf(a11[r], 0.f));
        }
    }
}

// ---- conv2+conv3+conv4+pool fused (grid 100, ping-pong LDS) --------------------
__global__ __launch_bounds__(256) void conv234_pool_kernel(
    const short* __restrict__ C1, const float* __restrict__ w2,
    const float* __restrict__ w3, const float* __restrict__ w4,
    const float* __restrict__ sup, const float* __restrict__ qry,
    const float* __restrict__ RFAC, float* __restrict__ out) {
    __shared__ __align__(16) short inTA[144 * 40];  // 11.5 KB
    __shared__ __align__(16) short inTB[144 * 40];  // 11.5 KB
    __shared__ __align__(16) short Wt[9 * 32 * 40]; // 23.0 KB (restaged per conv)
    __shared__ float sig[32 * 104];                 // 13.3 KB
    __shared__ float rfacL[104];
    const int b = blockIdx.x;
    const int t = threadIdx.x;
    const int wave = t >> 6, lane = t & 63;
    const int quad = lane >> 4, c16 = lane & 15;
    const float* feat = (b < 25) ? (sup + (size_t)b * 12800) : (qry + (size_t)(b - 25) * 12800);
    for (int i = t; i < 720; i += 256) {
        short8 z;
        #pragma unroll
        for (int j = 0; j < 8; ++j) z[j] = 0;
        *(short8*)&inTA[i * 8] = z;
        *(short8*)&inTB[i * 8] = z;
    }
    if (t < 100) rfacL[t] = RFAC[b * 100 + t];
    __syncthreads();
    for (int idx = t; idx < 200; idx += 256) {
        int pp = idx >> 1, half = idx & 1;
        int pos = (pp / 10 + 1) * 12 + (pp % 10) + 1;
        const short8* sp = (const short8*)(C1 + ((size_t)b * 100 + pp) * 32 + half * 16);
        *(short8*)&inTA[pos * 40 + half * 16]     = sp[0];
        *(short8*)&inTA[pos * 40 + half * 16 + 8] = sp[1];
    }
    const int m0 = wave * 32 + c16;
    const int m1 = m0 + 16;
    const int mc0 = (m0 < 100) ? m0 : 99, mc1 = (m1 < 100) ? m1 : 99;
    const int base0 = (mc0 / 10) * 12 + (mc0 % 10);
    const int base1 = (mc1 / 10) * 12 + (mc1 % 10);
    const int p0o = wave * 32 + quad * 4;
    f32x4 a00, a01, a10, a11;

#define STAGE_W(wptr)                                                        \
    for (int i = t; i < 9216; i += 256) {                                    \
        int j = i / 1024, rem = i - j * 1024;                                \
        int co = rem >> 5, ch = rem & 31;                                    \
        Wt[j * 1280 + co * 40 + ch] = f2bf((wptr)[(size_t)co * 288 + ch * 9 + j]); \
    }
#define CONV(src)                                                            \
    a00 = (f32x4){0.f,0.f,0.f,0.f}; a01 = (f32x4){0.f,0.f,0.f,0.f};          \
    a10 = (f32x4){0.f,0.f,0.f,0.f}; a11 = (f32x4){0.f,0.f,0.f,0.f};          \
    _Pragma("unroll")                                                        \
    for (int j = 0; j < 9; ++j) {                                            \
        const int offj = (j / 3) * 12 + (j % 3);                             \
        short8 af0 = *(const short8*)&(src)[(base0 + offj) * 40 + quad * 8]; \
        short8 af1 = *(const short8*)&(src)[(base1 + offj) * 40 + quad * 8]; \
        short8 bf0 = *(const short8*)&Wt[j * 1280 + c16 * 40 + quad * 8];    \
        short8 bf1 = *(const short8*)&Wt[j * 1280 + (16 + c16) * 40 + quad * 8]; \
        a00 = __builtin_amdgcn_mfma_f32_16x16x32_bf16(af0, bf0, a00, 0, 0, 0); \
        a01 = __builtin_amdgcn_mfma_f32_16x16x32_bf16(af0, bf1, a01, 0, 0, 0); \
        a10 = __builtin_amdgcn_mfma_f32_16x16x32_bf16(af1, bf0, a10, 0, 0, 0); \
        a11 = __builtin_amdgcn_mfma_f32_16x16x32_bf16(af1, bf1, a11, 0, 0, 0); \
    }
#define WRITE_RELU(dst)                                                      \
    _Pragma("unroll")                                                        \
    for (int r = 0; r < 4; ++r) {                                            \
        const int q0 = p0o + r, q1 = q0 + 16;                                \
        if (q0 < 100) {                                                      \
            int ps = (q0 / 10 + 1) * 12 + (q0 % 10) + 1;                     \
            (dst)[ps * 40 + c16]      = f2bf(fmaxf(a00[r], 0.f));            \
            (dst)[ps * 40 + 16 + c16] = f2bf(fmaxf(a01[r], 0.f));            \
        }                                                                    \
        if (q1 < 100) {                                                      \
            int ps = (q1 / 10 + 1) * 12 + (q1 % 10) + 1;                     \
            (dst)[ps * 40 + c16]      = f2bf(fmaxf(a10[r], 0.f));            \
            (dst)[ps * 40 + 16 + c16] = f2bf(fmaxf(a11[r], 0.f));            \
        }                                                                    \
    }

    STAGE_W(w2)
    __syncthreads();
    CONV(inTA)
    __syncthreads();
    WRITE_RELU(inTB)
    STAGE_W(w3)
    __syncthreads();
    CONV(inTB)
    __syncthreads();
    WRITE_RELU(inTA)
    STAGE_W(w4)
    __syncthreads();
    CONV(inTA)
    #pragma unroll
    for (int r = 0; r < 4; ++r) {
        const int q0 = p0o + r, q1 = q0 + 16;
        if (q0 < 100) {
            float rf = rfacL[q0];
            sig[c16 * 104 + q0]        = rf / (1.f + expf(-a00[r]));
            sig[(16 + c16) * 104 + q0] = rf / (1.f + expf(-a01[r]));
        }
        if (q1 < 100) {
            float rf = rfacL[q1];
            sig[c16 * 104 + q1]        = rf / (1.f + expf(-a10[r]));
            sig[(16 + c16) * 104 + q1] = rf / (1.f + expf(-a11[r]));
        }
    }
    __syncthreads();
    const int cc = t & 127, h = t >> 7;
    float accv[16];
    #pragma unroll
    for (int k = 0; k < 16; ++k) accv[k] = 0.f;
    const float* fp = feat + (size_t)cc * 100;
    for (int pp = 0; pp < 100; pp += 4) {
        float4 f4 = *(const float4*)&fp[pp];
        #pragma unroll
        for (int k = 0; k < 16; ++k) {
            const float* sg = &sig[(h + 2 * k) * 104 + pp];
            accv[k] += sg[0] * f4.x + sg[1] * f4.y + sg[2] * f4.z + sg[3] * f4.w;
        }
    }
    #pragma unroll
    for (int k = 0; k < 16; ++k)
        out[(size_t)b * 4096 + cc * 32 + (h + 2 * k)] = accv[k] * 0.01f;
#undef STAGE_W
#undef CONV
#undef WRITE_RELU
}

extern "C" void kernel_launch(void* const* d_in, const int* in_sizes, int n_in,
                              void* d_out, int out_size, void* d_ws, size_t ws_size,
                              hipStream_t stream) {
    (void)in_sizes; (void)n_in; (void)out_size; (void)ws_size;
    const float* sup    = (const float*)d_in[0];
    const float* qry    = (const float*)d_in[1];
    const float* td     = (const float*)d_in[2];
    const float* ln1_g  = (const float*)d_in[3];
    const float* ln1_b  = (const float*)d_in[4];
    const float* qkv_w  = (const float*)d_in[5];
    const float* qkv_b  = (const float*)d_in[6];
    const float* out_w  = (const float*)d_in[7];
    const float* out_b  = (const float*)d_in[8];
    const float* ln2_g  = (const float*)d_in[9];
    const float* ln2_b  = (const float*)d_in[10];
    const float* mlp_w1 = (const float*)d_in[11];
    const float* mlp_b1 = (const float*)d_in[12];
    const float* mlp_w2 = (const float*)d_in[13];
    const float* mlp_b2 = (const float*)d_in[14];
    const float* rg     = (const float*)d_in[15];
    const float* rb     = (const float*)d_in[16];
    const float* c1     = (const float*)d_in[17];
    const float* c2     = (const float*)d_in[18];
    const float* c3     = (const float*)d_in[19];
    const float* c4     = (const float*)d_in[20];
    float* out = (float*)d_out;

    float* ws    = (float*)d_ws;
    float* X     = ws;                       // 327680 f
    float* KEY0  = X + 327680;               // 2048 f
    float* RFAC  = KEY0 + 2048;              // 10000 f
    short* Hbf   = (short*)(RFAC + 10000);   // 327680 shorts (2560x128 bf16)
    short* Qbf   = Hbf + 327680;             // 327680
    short* Kbf   = Qbf + 327680;             // 327680
    short* VTb   = Kbf + 327680;             // 327680
    short* C1    = VTb + 327680;             // 320000 (100*100*32)
    float* PARTG = (float*)(C1 + 320000);    // 8*2560*128 floats (PART aliases)
    float* PART  = PARTG;

    const int SG = (SEQ + 7) / 8;            // 315
    const int MT = (SEQ + 63) / 64;          // 40

    concat_ln_kernel<<<SEQ, 64, 0, stream>>>(td, sup, ln1_g, ln1_b, X, Hbf);
    // ---- layer 0 (full) ----
    qkv_mfma_kernel<<<dim3(MT, 6), 256, 0, stream>>>(
        Hbf, qkv_w, qkv_b, Qbf, Kbf, VTb, MT);
    attn_kernel<<<dim3((SEQ + 31) / 32, 8, 2), 128, 0, stream>>>(Qbf, Kbf, VTb, PART);
    proj_merge_ln_kernel<<<SG, 512, 0, stream>>>(
        PART, out_w, out_b, X, X, Hbf, ln2_g, ln2_b, SEQ);
    mlp_fused_kernel<<<dim3(MT, 8), 256, 0, stream>>>(
        Hbf, mlp_w1, mlp_b1, mlp_w2, PARTG);
    combine_ln_kernel<<<SG, 512, 0, stream>>>(
        PARTG, mlp_b2, X, X, Hbf, ln1_g + 128, ln1_b + 128, 16, KEY0);
    // ---- layer 1 (only rows 0..15 of output are consumed via key0) ----
    qkv_mfma_kernel<<<dim3(MT, 6), 256, 0, stream>>>(
        Hbf, qkv_w + (size_t)128 * 384, qkv_b + 384, Qbf, Kbf, VTb, 1);
    attn_kernel<<<dim3(1, 8, 2), 128, 0, stream>>>(Qbf, Kbf, VTb, PART);
    pml16_kernel<<<8, 512, 0, stream>>>(
        PART, out_w + 128 * 128, out_b + 128, ln2_g + 128, ln2_b + 128,
        mlp_w1 + (size_t)128 * 512, mlp_b1 + 512, mlp_w2 + (size_t)512 * 128,
        mlp_b2 + 128, X, KEY0);
    // ---- conv tail ----
    region_conv1_kernel<<<100, 256, 0, stream>>>(sup, qry, KEY0, rg, rb, c1, C1, RFAC);
    conv234_pool_kernel<<<100, 256, 0, stream>>>(C1, c2, c3, c4, sup, qry, RFAC, out);
}

// Round 10
// 258.077 us; speedup vs baseline: 1.1787x; 1.0168x over previous
//
#include <hip/hip_runtime.h>
#include <math.h>

#define SEQ 2516
#define SEQP 2520
#define SEQP2 2560
#define CDIM 128

typedef __attribute__((ext_vector_type(8))) short short8;
typedef __attribute__((ext_vector_type(4))) float f32x4;

__device__ __forceinline__ float gelu_exact(float x) {
    return x * 0.5f * (1.0f + erff(x * 0.7071067811865475f));
}
__device__ __forceinline__ float fexp2(float x) { return __builtin_amdgcn_exp2f(x); }
__device__ __forceinline__ short f2bf(float f) {     // fp32 -> bf16 RNE
    unsigned u = __float_as_uint(f);
    unsigned r = 0x7fffu + ((u >> 16) & 1u);
    return (short)((u + r) >> 16);
}
__device__ __forceinline__ short f2bf_trunc(float f) {   // for P (e>=0): 1 op
    return (short)(__float_as_uint(f) >> 16);
}

// ------------- concat + LN1(layer0): one wave per row; H stored bf16 ------------
__global__ __launch_bounds__(64) void concat_ln_kernel(
    const float* __restrict__ td, const float* __restrict__ sup,
    const float* __restrict__ g, const float* __restrict__ b,
    float* __restrict__ X, short* __restrict__ Hbf) {
    const int row = blockIdx.x;
    const int t = threadIdx.x;
    float x0, x1;
    if (row < 16) {
        x0 = td[row * 128 + t];
        x1 = td[row * 128 + 64 + t];
    } else {
        int r = row - 16;
        int n = r / 100, p = r - n * 100;
        x0 = sup[n * 12800 + t * 100 + p];
        x1 = sup[n * 12800 + (t + 64) * 100 + p];
    }
    X[row * 128 + t] = x0;
    X[row * 128 + 64 + t] = x1;
    float s = x0 + x1;
    for (int off = 32; off > 0; off >>= 1) s += __shfl_down(s, off);
    float mean = __shfl(s, 0) * (1.f / 128.f);
    float d0 = x0 - mean, d1 = x1 - mean;
    float v = d0 * d0 + d1 * d1;
    for (int off = 32; off > 0; off >>= 1) v += __shfl_down(v, off);
    float var = __shfl(v, 0) * (1.f / 128.f);
    float rstd = rsqrtf(var + 1e-5f);
    Hbf[row * 128 + t]      = f2bf(d0 * rstd * g[t] + b[t]);
    Hbf[row * 128 + 64 + t] = f2bf(d1 * rstd * g[t + 64] + b[t + 64]);
}

// ---- qkv MFMA GEMM: A is pre-converted bf16 (Hbf). Writes Q/K bf16, V^T bf16 ---
__global__ __launch_bounds__(256) void qkv_mfma_kernel(
    const short* __restrict__ A, const float* __restrict__ W,
    const float* __restrict__ bias,
    short* __restrict__ Qbf, short* __restrict__ Kbf, short* __restrict__ VTb,
    int q_mt) {
    if (blockIdx.y < 2 && (int)blockIdx.x >= q_mt) return;   // uniform: whole block
    __shared__ __align__(16) short Wt[64 * 136];   // 17.4 KB
    const int t = threadIdx.x;
    const int wave = t >> 6, lane = t & 63;
    const int quad = lane >> 4, c16 = lane & 15;
    const int m0 = blockIdx.x * 64;
    const int n0 = blockIdx.y * 64;
    const float SC = 0.25f * 1.4426950408889634f;   // folded into Q
    #pragma unroll
    for (int pass = 0; pass < 4; ++pass) {
        int idx = t + pass * 256;
        int n = idx & 63, kc = idx >> 6;
        short8 wv;
        #pragma unroll
        for (int j = 0; j < 8; ++j)
            wv[j] = f2bf(W[(size_t)(kc * 8 + j) * 384 + n0 + n]);
        *(short8*)&Wt[n * 136 + kc * 8] = wv;
    }
    __syncthreads();
    const int am = m0 + wave * 16 + c16;
    f32x4 acc[4];
    #pragma unroll
    for (int i = 0; i < 4; ++i) acc[i] = (f32x4){0.f, 0.f, 0.f, 0.f};
    #pragma unroll
    for (int kk = 0; kk < 4; ++kk) {
        short8 af = *(const short8*)(A + (size_t)am * 128 + kk * 32 + quad * 8);
        #pragma unroll
        for (int ns = 0; ns < 4; ++ns) {
            short8 wf = *(const short8*)&Wt[(ns * 16 + c16) * 136 + kk * 32 + quad * 8];
            acc[ns] = __builtin_amdgcn_mfma_f32_16x16x32_bf16(af, wf, acc[ns], 0, 0, 0);
        }
    }
    const int region = __builtin_amdgcn_readfirstlane(n0 >> 7);  // 0 Q, 1 K, 2 V
    #pragma unroll
    for (int ns = 0; ns < 4; ++ns) {
        const int n = n0 + ns * 16 + c16;
        float bv = bias[n];
        #pragma unroll
        for (int r = 0; r < 4; ++r) {
            const int row = m0 + wave * 16 + quad * 4 + r;
            float v = acc[ns][r] + bv;
            if (region == 0)      Qbf[(size_t)row * 128 + n] = f2bf(v * SC);
            else if (region == 1) Kbf[(size_t)row * 128 + (n - 128)] = f2bf(v);
            else                  VTb[(size_t)(n - 256) * SEQP2 + row] = f2bf(v);
        }
    }
}

// ---- attention: bf16 MFMA flash, pre-converted inputs, param split-K -----------
// ztiles = K/V tiles per z-split. Layer 0: ztiles=10, z-grid 2 (identical to the
// proven config). Layer 1: ztiles=5, z-grid 4 (halves serial depth; merge is 4-way
// in pml16). PART slice index = z*8+head.
__global__ __launch_bounds__(128) void attn_kernel(
    const short* __restrict__ Qbf, const short* __restrict__ Kbf,
    const short* __restrict__ VTb, float* __restrict__ PART, int ztiles) {
    __shared__ __align__(16) short sKs[9600];  // Ks 128*24 | Vt 16*136 | P 2*16*136
    short* Ks = sKs;
    short* Vt = sKs + 3072;
    const int t = threadIdx.x;
    const int wave = t >> 6, lane = t & 63;
    const int quad = lane >> 4, c16 = lane & 15;
    short* Pw = sKs + 3072 + 2176 + wave * 16 * 136;
    const int head = blockIdx.y, z = blockIdx.z;
    const int qb = blockIdx.x * 32 + wave * 16;

    short8 qf;
    #pragma unroll
    for (int i = 0; i < 8; ++i) qf[i] = 0;
    if (quad < 2)
        qf = *(const short8*)(Qbf + (size_t)(qb + c16) * 128 + head * 16 + quad * 8);
    f32x4 oacc = {0.f, 0.f, 0.f, 0.f};
    float m_[4] = {-INFINITY, -INFINITY, -INFINITY, -INFINITY};
    float l_[4] = {0.f, 0.f, 0.f, 0.f};

    const int vdim = t >> 3, vseg = t & 7;
    const int tA = z * ztiles;
    const int tB = (tA + ztiles > 20) ? 20 : tA + ztiles;
    for (int ti = tA; ti < tB; ++ti) {
        const int tile0 = ti * 128;
        if (ti != tA) __syncthreads();
        {
            const short8* kp = (const short8*)(Kbf + (size_t)(tile0 + t) * 128 + head * 16);
            *(short8*)&Ks[t * 24]     = kp[0];
            *(short8*)&Ks[t * 24 + 8] = kp[1];
            const short8* vp = (const short8*)(VTb + (size_t)(head * 16 + vdim) * SEQP2 + tile0 + vseg * 16);
            *(short8*)&Vt[vdim * 136 + vseg * 16]     = vp[0];
            *(short8*)&Vt[vdim * 136 + vseg * 16 + 8] = vp[1];
        }
        __syncthreads();

        f32x4 sA[4], sB[4];
        #pragma unroll
        for (int st = 0; st < 4; ++st) {
            const int k0 = st * 32;
            short8 kfA, kfB;
            #pragma unroll
            for (int i = 0; i < 8; ++i) { kfA[i] = 0; kfB[i] = 0; }
            if (quad < 2) {
                kfA = *(const short8*)&Ks[(k0 + c16) * 24 + quad * 8];
                kfB = *(const short8*)&Ks[(k0 + 16 + c16) * 24 + quad * 8];
            }
            f32x4 zz = {0.f, 0.f, 0.f, 0.f};
            sA[st] = __builtin_amdgcn_mfma_f32_16x16x32_bf16(qf, kfA, zz, 0, 0, 0);
            sB[st] = __builtin_amdgcn_mfma_f32_16x16x32_bf16(qf, kfB, zz, 0, 0, 0);
            const bool badA = (tile0 + k0 + c16) >= SEQ;
            const bool badB = (tile0 + k0 + 16 + c16) >= SEQ;
            if (badA) { sA[st][0] = -1e30f; sA[st][1] = -1e30f; sA[st][2] = -1e30f; sA[st][3] = -1e30f; }
            if (badB) { sB[st][0] = -1e30f; sB[st][1] = -1e30f; sB[st][2] = -1e30f; sB[st][3] = -1e30f; }
        }
        #pragma unroll
        for (int r = 0; r < 4; ++r) {
            float v = fmaxf(sA[0][r], sB[0][r]);
            #pragma unroll
            for (int st = 1; st < 4; ++st) v = fmaxf(v, fmaxf(sA[st][r], sB[st][r]));
            v = fmaxf(v, __shfl_xor(v, 1));
            v = fmaxf(v, __shfl_xor(v, 2));
            v = fmaxf(v, __shfl_xor(v, 4));
            v = fmaxf(v, __shfl_xor(v, 8));
            float nm = fmaxf(m_[r], v);
            float corr = fexp2(m_[r] - nm);
            m_[r] = nm;
            oacc[r] *= corr;
            l_[r] *= corr;
        }
        #pragma unroll
        for (int st = 0; st < 4; ++st) {
            #pragma unroll
            for (int r = 0; r < 4; ++r) {
                float eA = fexp2(sA[st][r] - m_[r]);
                float eB = fexp2(sB[st][r] - m_[r]);
                l_[r] += eA + eB;
                Pw[(quad * 4 + r) * 136 + st * 32 + c16]      = f2bf_trunc(eA);
                Pw[(quad * 4 + r) * 136 + st * 32 + 16 + c16] = f2bf_trunc(eB);
            }
        }
        #pragma unroll
        for (int st = 0; st < 4; ++st) {
            short8 pf = *(const short8*)&Pw[c16 * 136 + st * 32 + quad * 8];
            short8 vf = *(const short8*)&Vt[c16 * 136 + st * 32 + quad * 8];
            oacc = __builtin_amdgcn_mfma_f32_16x16x32_bf16(pf, vf, oacc, 0, 0, 0);
        }
    }
    #pragma unroll
    for (int r = 0; r < 4; ++r) {
        float lr = l_[r];
        lr += __shfl_xor(lr, 1);
        lr += __shfl_xor(lr, 2);
        lr += __shfl_xor(lr, 4);
        lr += __shfl_xor(lr, 8);
        const int qrow = qb + quad * 4 + r;
        if (qrow < SEQ) {
            float* dst = PART + ((size_t)(z * 8 + head) * SEQP + qrow) * 20;
            dst[c16] = oacc[r];
            if (c16 == 0) { dst[16] = m_[r]; dst[17] = lr; }
        }
    }
}

// ---- proj GEMM fused with attn 2-way split merge + residual + row-LN -----------
__global__ __launch_bounds__(512) void proj_merge_ln_kernel(
    const float* __restrict__ PART, const float* __restrict__ W,
    const float* __restrict__ bias, const float* __restrict__ R,
    float* __restrict__ C, short* __restrict__ Hbf,
    const float* __restrict__ g, const float* __restrict__ bb, int M) {
    __shared__ float ln[8][130];
    const int t = threadIdx.x;
    const int c = t & 127;
    const int grp = __builtin_amdgcn_readfirstlane(t >> 7);
    const int r0 = blockIdx.x * 8 + grp * 2;
    float acc0 = 0.f, acc1 = 0.f;
    #pragma unroll
    for (int h = 0; h < 8; ++h) {
        const float* p0a = PART + ((size_t)h * SEQP + r0) * 20;
        const float* p1a = PART + ((size_t)(8 + h) * SEQP + r0) * 20;
        const float* p0b = p0a + 20;
        const float* p1b = p1a + 20;
        float m0 = p0a[16], l0 = p0a[17], m1 = p1a[16], l1 = p1a[17];
        float Ma = fmaxf(m0, m1);
        float w0 = fexp2(m0 - Ma), w1 = fexp2(m1 - Ma);
        float inva = 1.f / fmaf(l0, w0, l1 * w1);
        float c0a = w0 * inva, c1a = w1 * inva;
        m0 = p0b[16]; l0 = p0b[17]; m1 = p1b[16]; l1 = p1b[17];
        float Mb = fmaxf(m0, m1);
        w0 = fexp2(m0 - Mb); w1 = fexp2(m1 - Mb);
        float invb = 1.f / fmaf(l0, w0, l1 * w1);
        float c0b = w0 * invb, c1b = w1 * invb;
        #pragma unroll
        for (int kk = 0; kk < 4; ++kk) {
            const int k0 = h * 16 + kk * 4;
            float w_0 = W[(size_t)(k0 + 0) * 128 + c];
            float w_1 = W[(size_t)(k0 + 1) * 128 + c];
            float w_2 = W[(size_t)(k0 + 2) * 128 + c];
            float w_3 = W[(size_t)(k0 + 3) * 128 + c];
            float4 x0 = *(const float4*)&p0a[kk * 4];
            float4 y0 = *(const float4*)&p1a[kk * 4];
            float4 x1 = *(const float4*)&p0b[kk * 4];
            float4 y1 = *(const float4*)&p1b[kk * 4];
            float a00 = x0.x * c0a + y0.x * c1a;
            float a01 = x0.y * c0a + y0.y * c1a;
            float a02 = x0.z * c0a + y0.z * c1a;
            float a03 = x0.w * c0a + y0.w * c1a;
            float a10 = x1.x * c0b + y1.x * c1b;
            float a11 = x1.y * c0b + y1.y * c1b;
            float a12 = x1.z * c0b + y1.z * c1b;
            float a13 = x1.w * c0b + y1.w * c1b;
            acc0 = fmaf(a00, w_0, acc0); acc0 = fmaf(a01, w_1, acc0);
            acc0 = fmaf(a02, w_2, acc0); acc0 = fmaf(a03, w_3, acc0);
            acc1 = fmaf(a10, w_0, acc1); acc1 = fmaf(a11, w_1, acc1);
            acc1 = fmaf(a12, w_2, acc1); acc1 = fmaf(a13, w_3, acc1);
        }
    }
    float bv = bias[c];
    float v0 = acc0 + bv + R[(size_t)(r0 + 0) * 128 + c];
    float v1 = acc1 + bv + R[(size_t)(r0 + 1) * 128 + c];
    ln[grp * 2 + 0][c] = v0;
    ln[grp * 2 + 1][c] = v1;
    if (r0 + 0 < M) C[(size_t)(r0 + 0) * 128 + c] = v0;
    if (r0 + 1 < M) C[(size_t)(r0 + 1) * 128 + c] = v1;
    __syncthreads();
    const int wv = t >> 6, l = t & 63;
    float x0 = ln[wv][l], x1 = ln[wv][l + 64];
    float s = x0 + x1;
    for (int off = 32; off > 0; off >>= 1) s += __shfl_down(s, off);
    float mean = __shfl(s, 0) * (1.f / 128.f);
    float d0 = x0 - mean, d1 = x1 - mean;
    float vv = d0 * d0 + d1 * d1;
    for (int off = 32; off > 0; off >>= 1) vv += __shfl_down(vv, off);
    float var = __shfl(vv, 0) * (1.f / 128.f);
    float rstd = rsqrtf(var + 1e-5f);
    const int hrow = blockIdx.x * 8 + wv;
    Hbf[(size_t)hrow * 128 + l]      = f2bf(d0 * rstd * g[l] + bb[l]);
    Hbf[(size_t)hrow * 128 + 64 + l] = f2bf(d1 * rstd * g[l + 64] + bb[l + 64]);
}

// ---- FUSED mlp1+mlp2-kpart: grid (M-tiles, 8 kz); A is bf16 (Hbf) --------------
__global__ __launch_bounds__(256) void mlp_fused_kernel(
    const short* __restrict__ A, const float* __restrict__ W1,
    const float* __restrict__ b1, const float* __restrict__ W2,
    float* __restrict__ PARTG) {
    __shared__ __align__(16) short W1t[64 * 136];   // 17.4 KB
    __shared__ __align__(16) short W2t[128 * 72];   // 18.4 KB
    __shared__ __align__(16) short Ct[4 * 16 * 72]; //  9.2 KB (per-wave 16x72)
    const int t = threadIdx.x;
    const int wave = t >> 6, lane = t & 63;
    const int quad = lane >> 4, c16 = lane & 15;
    const int m0 = blockIdx.x * 64;
    const int kz = blockIdx.y;
    const int n0 = kz * 64;
    #pragma unroll
    for (int pass = 0; pass < 4; ++pass) {
        int idx = t + pass * 256;
        int n = idx & 63, kc = idx >> 6;
        short8 wv;
        #pragma unroll
        for (int j = 0; j < 8; ++j)
            wv[j] = f2bf(W1[(size_t)(kc * 8 + j) * 512 + n0 + n]);
        *(short8*)&W1t[n * 136 + kc * 8] = wv;
    }
    {
        const int n = t & 127, half = t >> 7;
        #pragma unroll
        for (int c = 0; c < 4; ++c) {
            short8 wv;
            #pragma unroll
            for (int j = 0; j < 8; ++j)
                wv[j] = f2bf(W2[(size_t)(n0 + half * 32 + c * 8 + j) * 128 + n]);
            *(short8*)&W2t[n * 72 + half * 32 + c * 8] = wv;
        }
    }
    __syncthreads();
    const int am = m0 + wave * 16 + c16;
    f32x4 acc1[4];
    #pragma unroll
    for (int i = 0; i < 4; ++i) acc1[i] = (f32x4){0.f, 0.f, 0.f, 0.f};
    #pragma unroll
    for (int kk = 0; kk < 4; ++kk) {
        short8 af = *(const short8*)(A + (size_t)am * 128 + kk * 32 + quad * 8);
        #pragma unroll
        for (int ns = 0; ns < 4; ++ns) {
            short8 wf = *(const short8*)&W1t[(ns * 16 + c16) * 136 + kk * 32 + quad * 8];
            acc1[ns] = __builtin_amdgcn_mfma_f32_16x16x32_bf16(af, wf, acc1[ns], 0, 0, 0);
        }
    }
    short* Cw = Ct + wave * 16 * 72;
    #pragma unroll
    for (int ns = 0; ns < 4; ++ns) {
        float bv = b1[n0 + ns * 16 + c16];
        #pragma unroll
        for (int r = 0; r < 4; ++r)
            Cw[(quad * 4 + r) * 72 + ns * 16 + c16] = f2bf(gelu_exact(acc1[ns][r] + bv));
    }
    f32x4 acc2[8];
    #pragma unroll
    for (int i = 0; i < 8; ++i) acc2[i] = (f32x4){0.f, 0.f, 0.f, 0.f};
    #pragma unroll
    for (int kk = 0; kk < 2; ++kk) {
        short8 af2 = *(const short8*)&Cw[c16 * 72 + kk * 32 + quad * 8];
        #pragma unroll
        for (int ns = 0; ns < 8; ++ns) {
            short8 wf = *(const short8*)&W2t[(ns * 16 + c16) * 72 + kk * 32 + quad * 8];
            acc2[ns] = __builtin_amdgcn_mfma_f32_16x16x32_bf16(af2, wf, acc2[ns], 0, 0, 0);
        }
    }
    float* dst = PARTG + (size_t)kz * SEQP2 * 128;
    #pragma unroll
    for (int ns = 0; ns < 8; ++ns) {
        #pragma unroll
        for (int r = 0; r < 4; ++r) {
            const int row = m0 + wave * 16 + quad * 4 + r;
            dst[(size_t)row * 128 + ns * 16 + c16] = acc2[ns][r];
        }
    }
}

// ---- combine 8 K-split partials + bias + residual + row-LN (+optional zero) ----
__global__ __launch_bounds__(512) void combine_ln_kernel(
    const float* __restrict__ PARTG, const float* __restrict__ bias,
    const float* __restrict__ R, float* __restrict__ C, short* __restrict__ Hbf,
    const float* __restrict__ g, const float* __restrict__ bb, int M,
    float* __restrict__ zk) {
    __shared__ float ln[8][130];
    const int t = threadIdx.x;
    if (zk != nullptr && blockIdx.x == 0) {
        #pragma unroll
        for (int i = 0; i < 4; ++i) zk[t + i * 512] = 0.f;
    }
    const int c = t & 127;
    const int grp = __builtin_amdgcn_readfirstlane(t >> 7);
    const int r0 = blockIdx.x * 8 + grp * 2;
    #pragma unroll
    for (int i = 0; i < 2; ++i) {
        const int row = r0 + i;
        float v = bias[c] + R[(size_t)row * 128 + c];
        #pragma unroll
        for (int kz = 0; kz < 8; ++kz)
            v += PARTG[(size_t)kz * SEQP2 * 128 + (size_t)row * 128 + c];
        ln[grp * 2 + i][c] = v;
        if (row < M) C[(size_t)row * 128 + c] = v;
    }
    __syncthreads();
    const int wv = t >> 6, l = t & 63;
    float x0 = ln[wv][l], x1 = ln[wv][l + 64];
    float s = x0 + x1;
    for (int off = 32; off > 0; off >>= 1) s += __shfl_down(s, off);
    float mean = __shfl(s, 0) * (1.f / 128.f);
    float d0 = x0 - mean, d1 = x1 - mean;
    float vv = d0 * d0 + d1 * d1;
    for (int off = 32; off > 0; off >>= 1) vv += __shfl_down(vv, off);
    float var = __shfl(vv, 0) * (1.f / 128.f);
    float rstd = rsqrtf(var + 1e-5f);
    const int hrow = blockIdx.x * 8 + wv;
    Hbf[(size_t)hrow * 128 + l]      = f2bf(d0 * rstd * g[l] + bb[l]);
    Hbf[(size_t)hrow * 128 + 64 + l] = f2bf(d1 * rstd * g[l + 64] + bb[l + 64]);
}

// ---- LAYER-1 TAIL: 4-way attn merge + proj + LN (16 rows) + MLP kz-slice -------
__global__ __launch_bounds__(512) void pml16_kernel(
    const float* __restrict__ PART, const float* __restrict__ Wo,
    const float* __restrict__ ob, const float* __restrict__ g2,
    const float* __restrict__ bl2, const float* __restrict__ W1,
    const float* __restrict__ b1, const float* __restrict__ W2,
    const float* __restrict__ b2, const float* __restrict__ X,
    float* __restrict__ KEY0) {
    __shared__ __align__(16) char SMEM[4352 + 51328];
    short* hA   = (short*)SMEM;                  // 16 x 136 bf16 (persistent)
    char*  U    = SMEM + 4352;                   // union region
    float* PARTL = (float*)U;                    // 10240 f [z4*h8 slices][row16][20]
    float* coefL = PARTL + 10240;                // 512 f   [row16][h8][z4]
    float* xpL   = coefL + 512;                  // 16*130 f
    short* W1t  = (short*)U;                     // 64*136
    short* W2t  = W1t + 8704;                    // 128*72
    short* Ct   = W2t + 9216;                    // 16*72
    const int t = threadIdx.x;
    const int kz = blockIdx.x;

    // stage PART rows 0..15 for all 32 (z,head) slices
    for (int i = t; i < 10240; i += 512) {
        int sh = i / 320, rem = i - sh * 320;
        PARTL[i] = PART[((size_t)sh * SEQP) * 20 + rem];
    }
    __syncthreads();
    if (t < 128) {
        int row = t >> 3, h = t & 7;
        float m[4], l[4];
        #pragma unroll
        for (int z = 0; z < 4; ++z) {
            m[z] = PARTL[(z * 8 + h) * 320 + row * 20 + 16];
            l[z] = PARTL[(z * 8 + h) * 320 + row * 20 + 17];
        }
        float Mx = fmaxf(fmaxf(m[0], m[1]), fmaxf(m[2], m[3]));
        float w[4], den = 0.f;
        #pragma unroll
        for (int z = 0; z < 4; ++z) { w[z] = fexp2(m[z] - Mx); den = fmaf(l[z], w[z], den); }
        float inv = 1.f / den;
        #pragma unroll
        for (int z = 0; z < 4; ++z) coefL[row * 32 + h * 4 + z] = w[z] * inv;
    }
    __syncthreads();
    // proj: each thread -> 4 rows (grp*4..+3) x col c
    const int c = t & 127;
    const int grp = t >> 7;
    float xv[4] = {0.f, 0.f, 0.f, 0.f};
    for (int h = 0; h < 8; ++h) {
        float cv0[4], cv1[4], cv2[4], cv3[4];
        #pragma unroll
        for (int i = 0; i < 4; ++i) {
            int row = grp * 4 + i;
            cv0[i] = coefL[row * 32 + h * 4 + 0];
            cv1[i] = coefL[row * 32 + h * 4 + 1];
            cv2[i] = coefL[row * 32 + h * 4 + 2];
            cv3[i] = coefL[row * 32 + h * 4 + 3];
        }
        #pragma unroll
        for (int d = 0; d < 16; ++d) {
            float w = Wo[(size_t)(h * 16 + d) * 128 + c];
            #pragma unroll
            for (int i = 0; i < 4; ++i) {
                int row = grp * 4 + i;
                float a = PARTL[(0 * 8 + h) * 320 + row * 20 + d] * cv0[i]
                        + PARTL[(1 * 8 + h) * 320 + row * 20 + d] * cv1[i]
                        + PARTL[(2 * 8 + h) * 320 + row * 20 + d] * cv2[i]
                        + PARTL[(3 * 8 + h) * 320 + row * 20 + d] * cv3[i];
                xv[i] = fmaf(a, w, xv[i]);
            }
        }
    }
    #pragma unroll
    for (int i = 0; i < 4; ++i) {
        int row = grp * 4 + i;
        float v = xv[i] + ob[c] + X[(size_t)row * 128 + c];
        xpL[row * 130 + c] = v;
        if (kz == 0) atomicAdd(&KEY0[row * 128 + c], v + b2[c]);
    }
    __syncthreads();
    // row-LN -> hA bf16 (each wave: 2 rows)
    {
        const int wv6 = t >> 6, l = t & 63;
        #pragma unroll
        for (int rr = 0; rr < 2; ++rr) {
            int row = wv6 * 2 + rr;
            float x0 = xpL[row * 130 + l], x1 = xpL[row * 130 + 64 + l];
            float s = x0 + x1;
            s += __shfl_xor(s, 1); s += __shfl_xor(s, 2); s += __shfl_xor(s, 4);
            s += __shfl_xor(s, 8); s += __shfl_xor(s, 16); s += __shfl_xor(s, 32);
            float mean = s * (1.f / 128.f);
            float d0 = x0 - mean, d1 = x1 - mean;
            float vv = d0 * d0 + d1 * d1;
            vv += __shfl_xor(vv, 1); vv += __shfl_xor(vv, 2); vv += __shfl_xor(vv, 4);
            vv += __shfl_xor(vv, 8); vv += __shfl_xor(vv, 16); vv += __shfl_xor(vv, 32);
            float rstd = rsqrtf(vv * (1.f / 128.f) + 1e-5f);
            hA[row * 136 + l]      = f2bf(d0 * rstd * g2[l] + bl2[l]);
            hA[row * 136 + 64 + l] = f2bf(d1 * rstd * g2[64 + l] + bl2[64 + l]);
        }
    }
    __syncthreads();   // xpL/PARTL dead; reuse U for weights
    // stage W1 slice [128k][64n] and W2 slice [64k][128n]
    for (int idx = t; idx < 1024; idx += 512) {
        int n = idx & 63, kc = idx >> 6;
        short8 wv;
        #pragma unroll
        for (int j = 0; j < 8; ++j)
            wv[j] = f2bf(W1[(size_t)(kc * 8 + j) * 512 + kz * 64 + n]);
        *(short8*)&W1t[n * 136 + kc * 8] = wv;
    }
    for (int idx = t; idx < 1024; idx += 512) {
        int n = idx & 127, kc = idx >> 7;
        short8 wv;
        #pragma unroll
        for (int j = 0; j < 8; ++j)
            wv[j] = f2bf(W2[(size_t)(kz * 64 + kc * 8 + j) * 128 + n]);
        *(short8*)&W2t[n * 72 + kc * 8] = wv;
    }
    __syncthreads();
    if (t < 64) {
        const int quad = t >> 4, c16 = t & 15;
        f32x4 acc1[4];
        #pragma unroll
        for (int i = 0; i < 4; ++i) acc1[i] = (f32x4){0.f, 0.f, 0.f, 0.f};
        #pragma unroll
        for (int kk = 0; kk < 4; ++kk) {
            short8 af = *(const short8*)&hA[c16 * 136 + kk * 32 + quad * 8];
            #pragma unroll
            for (int ns = 0; ns < 4; ++ns) {
                short8 wf = *(const short8*)&W1t[(ns * 16 + c16) * 136 + kk * 32 + quad * 8];
                acc1[ns] = __builtin_amdgcn_mfma_f32_16x16x32_bf16(af, wf, acc1[ns], 0, 0, 0);
            }
        }
        #pragma unroll
        for (int ns = 0; ns < 4; ++ns) {
            float bv = b1[kz * 64 + ns * 16 + c16];
            #pragma unroll
            for (int r = 0; r < 4; ++r)
                Ct[(quad * 4 + r) * 72 + ns * 16 + c16] = f2bf(gelu_exact(acc1[ns][r] + bv));
        }
        f32x4 acc2[8];
        #pragma unroll
        for (int i = 0; i < 8; ++i) acc2[i] = (f32x4){0.f, 0.f, 0.f, 0.f};
        #pragma unroll
        for (int kk = 0; kk < 2; ++kk) {
            short8 af2 = *(const short8*)&Ct[c16 * 72 + kk * 32 + quad * 8];
            #pragma unroll
            for (int ns = 0; ns < 8; ++ns) {
                short8 wf = *(const short8*)&W2t[(ns * 16 + c16) * 72 + kk * 32 + quad * 8];
                acc2[ns] = __builtin_amdgcn_mfma_f32_16x16x32_bf16(af2, wf, acc2[ns], 0, 0, 0);
            }
        }
        #pragma unroll
        for (int ns = 0; ns < 8; ++ns) {
            #pragma unroll
            for (int r = 0; r < 4; ++r)
                atomicAdd(&KEY0[(quad * 4 + r) * 128 + ns * 16 + c16], acc2[ns][r]);
        }
    }
}

// ---- region + stats + conv1-MFMA fused (grid 100) ------------------------------
__global__ __launch_bounds__(256) void region_conv1_kernel(
    const float* __restrict__ sup, const float* __restrict__ qry,
    const float* __restrict__ KEY0, const float* __restrict__ rg,
    const float* __restrict__ rb, const float* __restrict__ w,
    short* __restrict__ C1, float* __restrict__ RFAC) {
    __shared__ float key0L[2048];
    __shared__ float rfacL[104], MEANL[104], RSTDL[104];
    __shared__ __align__(16) short inT[144 * 136];  // 39.2 KB
    __shared__ __align__(16) short Wt[32 * 136];    //  8.7 KB
    const int b = blockIdx.x;
    const int t = threadIdx.x;
    const int wave = t >> 6, lane = t & 63;
    const int quad = lane >> 4, c16 = lane & 15;
    const float* feat = (b < 25) ? (sup + (size_t)b * 12800) : (qry + (size_t)(b - 25) * 12800);
    for (int i = t; i < 2048; i += 256) key0L[i] = KEY0[i];
    for (int i = t; i < 2448; i += 256) {    // zero inT (halo must stay 0)
        short8 z;
        #pragma unroll
        for (int j = 0; j < 8; ++j) z[j] = 0;
        *(short8*)&inT[i * 8] = z;
    }
    __syncthreads();
    if (t < 100) {
        float dots[16];
        #pragma unroll
        for (int mm = 0; mm < 16; ++mm) dots[mm] = 0.f;
        float s = 0.f, ss = 0.f;
        for (int c = 0; c < 128; ++c) {
            float f = feat[c * 100 + t];
            s += f; ss = fmaf(f, f, ss);
            #pragma unroll
            for (int mm = 0; mm < 16; ++mm) dots[mm] = fmaf(f, key0L[mm * 128 + c], dots[mm]);
        }
        float m16 = 0.f;
        #pragma unroll
        for (int mm = 0; mm < 16; ++mm) m16 += 1.f / (1.f + expf(-dots[mm] * (1.f / 128.f)));
        float r = m16 * (1.f / 16.f) + 1.f;
        rfacL[t] = r;
        RFAC[b * 100 + t] = r;
        float mr = s * (1.f / 128.f);
        float vr = ss * (1.f / 128.f) - mr * mr;
        MEANL[t] = mr * r;
        RSTDL[t] = rsqrtf(vr * r * r + 1e-6f);
    }
    __syncthreads();
    for (int i = t; i < 12800; i += 256) {
        int cc = i / 100, p = i - cc * 100;
        float v = feat[i] * rfacL[p];
        float lnv = (v - MEANL[p]) * RSTDL[p] * rg[cc] + rb[cc];
        int pos = (p / 10 + 1) * 12 + (p % 10) + 1;
        inT[pos * 136 + cc] = f2bf(lnv);
    }
    const int m0 = wave * 32 + c16;
    const int m1 = m0 + 16;
    const int mc0 = (m0 < 100) ? m0 : 99, mc1 = (m1 < 100) ? m1 : 99;
    const int base0 = (mc0 / 10) * 12 + (mc0 % 10);
    const int base1 = (mc1 / 10) * 12 + (mc1 % 10);
    f32x4 a00 = {0.f,0.f,0.f,0.f}, a01 = {0.f,0.f,0.f,0.f};
    f32x4 a10 = {0.f,0.f,0.f,0.f}, a11 = {0.f,0.f,0.f,0.f};
    for (int j = 0; j < 9; ++j) {
        __syncthreads();
        for (int i = t; i < 4096; i += 256) {
            int co = i >> 7, cin = i & 127;
            Wt[co * 136 + cin] = f2bf(w[(size_t)(co * 128 + cin) * 9 + j]);
        }
        __syncthreads();
        const int offj = (j / 3) * 12 + (j % 3);
        #pragma unroll
        for (int kk = 0; kk < 4; ++kk) {
            short8 af0 = *(const short8*)&inT[(base0 + offj) * 136 + kk * 32 + quad * 8];
            short8 af1 = *(const short8*)&inT[(base1 + offj) * 136 + kk * 32 + quad * 8];
            short8 bf0 = *(const short8*)&Wt[c16 * 136 + kk * 32 + quad * 8];
            short8 bf1 = *(const short8*)&Wt[(16 + c16) * 136 + kk * 32 + quad * 8];
            a00 = __builtin_amdgcn_mfma_f32_16x16x32_bf16(af0, bf0, a00, 0, 0, 0);
            a01 = __builtin_amdgcn_mfma_f32_16x16x32_bf16(af0, bf1, a01, 0, 0, 0);
            a10 = __builtin_amdgcn_mfma_f32_16x16x32_bf16(af1, bf0, a10, 0, 0, 0);
            a11 = __builtin_amdgcn_mfma_f32_16x16x32_bf16(af1, bf1, a11, 0, 0, 0);
        }
    }
    #pragma unroll
    for (int r = 0; r < 4; ++r) {
        const int p0 = wave * 32 + quad * 4 + r;
        const int p1 = p0 + 16;
        if (p0 < 100) {
            C1[((size_t)b * 100 + p0) * 32 + c16]      = f2bf(fmaxf(a00[r], 0.f));
            C1[((size_t)b * 100 + p0) * 32 + 16 + c16] = f2bf(fmaxf(a01[r], 0.f));
        }
        if (p1 < 100) {
            C1[((size_t)b * 100 + p1) * 32 + c16]      = f2bf(fmaxf(a10[r], 0.f));
            C1[((size_t)b * 100 + p1) * 32 + 16 + c16] = f2bf(fmaxf(a11[r], 0.f));
        }
    }
}

// ---- conv2+conv3+conv4+pool fused (grid 100, ping-pong LDS) --------------------
__global__ __launch_bounds__(256) void conv234_pool_kernel(
    const short* __restrict__ C1, const float* __restrict__ w2,
    const float* __restrict__ w3, const float* __restrict__ w4,
    const float* __restrict__ sup, const float* __restrict__ qry,
    const float* __restrict__ RFAC, float* __restrict__ out) {
    __shared__ __align__(16) short inTA[144 * 40];  // 11.5 KB
    __shared__ __align__(16) short inTB[144 * 40];  // 11.5 KB
    __shared__ __align__(16) short Wt[9 * 32 * 40]; // 23.0 KB (restaged per conv)
    __shared__ float sig[32 * 104];                 // 13.3 KB
    __shared__ float rfacL[104];
    const int b = blockIdx.x;
    const int t = threadIdx.x;
    const int wave = t >> 6, lane = t & 63;
    const int quad = lane >> 4, c16 = lane & 15;
    const float* feat = (b < 25) ? (sup + (size_t)b * 12800) : (qry + (size_t)(b - 25) * 12800);
    for (int i = t; i < 720; i += 256) {
        short8 z;
        #pragma unroll
        for (int j = 0; j < 8; ++j) z[j] = 0;
        *(short8*)&inTA[i * 8] = z;
        *(short8*)&inTB[i * 8] = z;
    }
    if (t < 100) rfacL[t] = RFAC[b * 100 + t];
    __syncthreads();
    for (int idx = t; idx < 200; idx += 256) {
        int pp = idx >> 1, half = idx & 1;
        int pos = (pp / 10 + 1) * 12 + (pp % 10) + 1;
        const short8* sp = (const short8*)(C1 + ((size_t)b * 100 + pp) * 32 + half * 16);
        *(short8*)&inTA[pos * 40 + half * 16]     = sp[0];
        *(short8*)&inTA[pos * 40 + half * 16 + 8] = sp[1];
    }
    const int m0 = wave * 32 + c16;
    const int m1 = m0 + 16;
    const int mc0 = (m0 < 100) ? m0 : 99, mc1 = (m1 < 100) ? m1 : 99;
    const int base0 = (mc0 / 10) * 12 + (mc0 % 10);
    const int base1 = (mc1 / 10) * 12 + (mc1 % 10);
    const int p0o = wave * 32 + quad * 4;
    f32x4 a00, a01, a10, a11;

#define STAGE_W(wptr)                                                        \
    for (int i = t; i < 9216; i += 256) {                                    \
        int j = i / 1024, rem = i - j * 1024;                                \
        int co = rem >> 5, ch = rem & 31;                                    \
        Wt[j * 1280 + co * 40 + ch] = f2bf((wptr)[(size_t)co * 288 + ch * 9 + j]); \
    }
#define CONV(src)                                                            \
    a00 = (f32x4){0.f,0.f,0.f,0.f}; a01 = (f32x4){0.f,0.f,0.f,0.f};          \
    a10 = (f32x4){0.f,0.f,0.f,0.f}; a11 = (f32x4){0.f,0.f,0.f,0.f};          \
    _Pragma("unroll")                                                        \
    for (int j = 0; j < 9; ++j) {                                            \
        const int offj = (j / 3) * 12 + (j % 3);                             \
        short8 af0 = *(const short8*)&(src)[(base0 + offj) * 40 + quad * 8]; \
        short8 af1 = *(const short8*)&(src)[(base1 + offj) * 40 + quad * 8]; \
        short8 bf0 = *(const short8*)&Wt[j * 1280 + c16 * 40 + quad * 8];    \
        short8 bf1 = *(const short8*)&Wt[j * 1280 + (16 + c16) * 40 + quad * 8]; \
        a00 = __builtin_amdgcn_mfma_f32_16x16x32_bf16(af0, bf0, a00, 0, 0, 0); \
        a01 = __builtin_amdgcn_mfma_f32_16x16x32_bf16(af0, bf1, a01, 0, 0, 0); \
        a10 = __builtin_amdgcn_mfma_f32_16x16x32_bf16(af1, bf0, a10, 0, 0, 0); \
        a11 = __builtin_amdgcn_mfma_f32_16x16x32_bf16(af1, bf1, a11, 0, 0, 0); \
    }
#define WRITE_RELU(dst)                                                      \
    _Pragma("unroll")                                                        \
    for (int r = 0; r < 4; ++r) {                                            \
        const int q0 = p0o + r, q1 = q0 + 16;                                \
        if (q0 < 100) {                                                      \
            int ps = (q0 / 10 + 1) * 12 + (q0 % 10) + 1;                     \
            (dst)[ps * 40 + c16]      = f2bf(fmaxf(a00[r], 0.f));            \
            (dst)[ps * 40 + 16 + c16] = f2bf(fmaxf(a01[r], 0.f));            \
        }                                                                    \
        if (q1 < 100) {                                                      \
            int ps = (q1 / 10 + 1) * 12 + (q1 % 10) + 1;                     \
            (dst)[ps * 40 + c16]      = f2bf(fmaxf(a10[r], 0.f));            \
            (dst)[ps * 40 + 16 + c16] = f2bf(fmaxf(a11[r], 0.f));            \
        }                                                                    \
    }

    STAGE_W(w2)
    __syncthreads();
    CONV(inTA)
    __syncthreads();
    WRITE_RELU(inTB)
    STAGE_W(w3)
    __syncthreads();
    CONV(inTB)
    __syncthreads();
    WRITE_RELU(inTA)
    STAGE_W(w4)
    __syncthreads();
    CONV(inTA)
    #pragma unroll
    for (int r = 0; r < 4; ++r) {
        const int q0 = p0o + r, q1 = q0 + 16;
        if (q0 < 100) {
            float rf = rfacL[q0];
            sig[c16 * 104 + q0]        = rf / (1.f + expf(-a00[r]));
            sig[(16 + c16) * 104 + q0] = rf / (1.f + expf(-a01[r]));
        }
        if (q1 < 100) {
            float rf = rfacL[q1];
            sig[c16 * 104 + q1]        = rf / (1.f + expf(-a10[r]));
            sig[(16 + c16) * 104 + q1] = rf / (1.f + expf(-a11[r]));
        }
    }
    __syncthreads();
    const int cc = t & 127, h = t >> 7;
    float accv[16];
    #pragma unroll
    for (int k = 0; k < 16; ++k) accv[k] = 0.f;
    const float* fp = feat + (size_t)cc * 100;
    for (int pp = 0; pp < 100; pp += 4) {
        float4 f4 = *(const float4*)&fp[pp];
        #pragma unroll
        for (int k = 0; k < 16; ++k) {
            const float* sg = &sig[(h + 2 * k) * 104 + pp];
            accv[k] += sg[0] * f4.x + sg[1] * f4.y + sg[2] * f4.z + sg[3] * f4.w;
        }
    }
    #pragma unroll
    for (int k = 0; k < 16; ++k)
        out[(size_t)b * 4096 + cc * 32 + (h + 2 * k)] = accv[k] * 0.01f;
#undef STAGE_W
#undef CONV
#undef WRITE_RELU
}

extern "C" void kernel_launch(void* const* d_in, const int* in_sizes, int n_in,
                              void* d_out, int out_size, void* d_ws, size_t ws_size,
                              hipStream_t stream) {
    (void)in_sizes; (void)n_in; (void)out_size; (void)ws_size;
    const float* sup    = (const float*)d_in[0];
    const float* qry    = (const float*)d_in[1];
    const float* td     = (const float*)d_in[2];
    const float* ln1_g  = (const float*)d_in[3];
    const float* ln1_b  = (const float*)d_in[4];
    const float* qkv_w  = (const float*)d_in[5];
    const float* qkv_b  = (const float*)d_in[6];
    const float* out_w  = (const float*)d_in[7];
    const float* out_b  = (const float*)d_in[8];
    const float* ln2_g  = (const float*)d_in[9];
    const float* ln2_b  = (const float*)d_in[10];
    const float* mlp_w1 = (const float*)d_in[11];
    const float* mlp_b1 = (const float*)d_in[12];
    const float* mlp_w2 = (const float*)d_in[13];
    const float* mlp_b2 = (const float*)d_in[14];
    const float* rg     = (const float*)d_in[15];
    const float* rb     = (const float*)d_in[16];
    const float* c1     = (const float*)d_in[17];
    const float* c2     = (const float*)d_in[18];
    const float* c3     = (const float*)d_in[19];
    const float* c4     = (const float*)d_in[20];
    float* out = (float*)d_out;

    float* ws    = (float*)d_ws;
    float* X     = ws;                       // 327680 f
    float* KEY0  = X + 327680;               // 2048 f
    float* RFAC  = KEY0 + 2048;              // 10000 f
    short* Hbf   = (short*)(RFAC + 10000);   // 327680 shorts (2560x128 bf16)
    short* Qbf   = Hbf + 327680;             // 327680
    short* Kbf   = Qbf + 327680;             // 327680
    short* VTb   = Kbf + 327680;             // 327680
    short* C1    = VTb + 327680;             // 320000 (100*100*32)
    float* PARTG = (float*)(C1 + 320000);    // 8*2560*128 floats (PART aliases;
    float* PART  = PARTG;                    //  layer1 uses 32 slices = 1.6M f, fits)

    const int SG = (SEQ + 7) / 8;            // 315
    const int MT = (SEQ + 63) / 64;          // 40

    concat_ln_kernel<<<SEQ, 64, 0, stream>>>(td, sup, ln1_g, ln1_b, X, Hbf);
    // ---- layer 0 (full) ----
    qkv_mfma_kernel<<<dim3(MT, 6), 256, 0, stream>>>(
        Hbf, qkv_w, qkv_b, Qbf, Kbf, VTb, MT);
    attn_kernel<<<dim3((SEQ + 31) / 32, 8, 2), 128, 0, stream>>>(Qbf, Kbf, VTb, PART, 10);
    proj_merge_ln_kernel<<<SG, 512, 0, stream>>>(
        PART, out_w, out_b, X, X, Hbf, ln2_g, ln2_b, SEQ);
    mlp_fused_kernel<<<dim3(MT, 8), 256, 0, stream>>>(
        Hbf, mlp_w1, mlp_b1, mlp_w2, PARTG);
    combine_ln_kernel<<<SG, 512, 0, stream>>>(
        PARTG, mlp_b2, X, X, Hbf, ln1_g + 128, ln1_b + 128, 16, KEY0);
    // ---- layer 1 (only rows 0..15 of output are consumed via key0) ----
    qkv_mfma_kernel<<<dim3(MT, 6), 256, 0, stream>>>(
        Hbf, qkv_w + (size_t)128 * 384, qkv_b + 384, Qbf, Kbf, VTb, 1);
    attn_kernel<<<dim3(1, 8, 4), 128, 0, stream>>>(Qbf, Kbf, VTb, PART, 5);
    pml16_kernel<<<8, 512, 0, stream>>>(
        PART, out_w + 128 * 128, out_b + 128, ln2_g + 128, ln2_b + 128,
        mlp_w1 + (size_t)128 * 512, mlp_b1 + 512, mlp_w2 + (size_t)512 * 128,
        mlp_b2 + 128, X, KEY0);
    // ---- conv tail ----
    region_conv1_kernel<<<100, 256, 0, stream>>>(sup, qry, KEY0, rg, rb, c1, C1, RFAC);
    conv234_pool_kernel<<<100, 256, 0, stream>>>(C1, c2, c3, c4, sup, qry, RFAC, out);
}